// Round 3
// baseline (594.564 us; speedup 1.0000x reference)
//
#include <hip/hip_runtime.h>
#include <math.h>

#define N_NODES 50000
#define NPAD 50048               // 64 * 782, padded node count for tiled GEMMs
#define N_EDGES 500000
#define EP (N_EDGES + N_NODES)   // 550000
#define IN_F 128
#define HID 64
#define HEADS 4
#define ZD (HEADS * HID)         // 256
#define G_B 16
#define OUT_F 326000
#define NEG 0.2f
#define SCAN_BLK 256
#define NBLK_SCAN ((N_NODES + SCAN_BLK - 1) / SCAN_BLK)   // 196
#define CAP 64                   // LDS-stash cap per dst
#define EVS 72                   // per-head LDS stride
#define NT 64                    // node tile for GEMM kernels
#define KP 68                    // padded k-row stride (mult of 4 for b128)

// ---------------- init + weight prep (merged: both trivially parallel) ----------
// Wstk[l][(h*64+k)][f] = 0.25 * W_gat[l][k][h*64+f]   (so h_next = relu(U@Wstk + b))
// weff_s[l][h][i] = sum_f W_gat[l][i][h*64+f] * att_src[l][h][f]   (al_s = h . weff_s)
__global__ void k_init(int* counts, int* cursor, float* pool, float* pool_cnt,
                       const float* __restrict__ W_gat, const float* __restrict__ att_src,
                       const float* __restrict__ att_dst, float* __restrict__ Wstk,
                       float* __restrict__ weff_s, float* __restrict__ weff_d) {
    int idx = blockIdx.x * 256 + threadIdx.x;
    if (idx < N_NODES) { counts[idx] = 1; cursor[idx] = 0; }
    if (idx < G_B * HID) pool[idx] = 0.f;
    if (idx < G_B) pool_cnt[idx] = 0.f;
    if (idx < 3 * ZD * HID) {
        int l = idx / (ZD * HID);
        int rem = idx - l * (ZD * HID);
        int hk = rem >> 6;            // 0..255  (h*64 + k)
        int f = rem & 63;
        int hh = hk >> 6, k = hk & 63;
        Wstk[idx] = 0.25f * W_gat[(size_t)l * HID * ZD + (size_t)k * ZD + hh * HID + f];
    }
    if (idx < 3 * HEADS * HID) {
        int l = idx / (HEADS * HID);
        int rem = idx - l * (HEADS * HID);
        int hh = rem >> 6, i = rem & 63;
        const float* Wl = W_gat + (size_t)l * HID * ZD;
        const float* as = att_src + l * HEADS * HID + hh * HID;
        const float* ad = att_dst + l * HEADS * HID + hh * HID;
        float ss = 0.f, sd = 0.f;
        for (int f = 0; f < HID; f++) {
            float wv = Wl[(size_t)i * ZD + hh * HID + f];
            ss += wv * as[f];
            sd += wv * ad[f];
        }
        weff_s[idx] = ss;
        weff_d[idx] = sd;
    }
}

__global__ void k_count(const int* __restrict__ ei, int* __restrict__ counts) {
    int i = blockIdx.x * 256 + threadIdx.x;
    if (i < N_EDGES) atomicAdd(&counts[ei[N_EDGES + i]], 1);
}

__global__ void k_scan1(const int* __restrict__ counts, int* __restrict__ tmp,
                        int* __restrict__ partial) {
    __shared__ int s[SCAN_BLK];
    int t = threadIdx.x;
    int i = blockIdx.x * SCAN_BLK + t;
    int v = (i < N_NODES) ? counts[i] : 0;
    s[t] = v;
    __syncthreads();
    for (int off = 1; off < SCAN_BLK; off <<= 1) {
        int a = (t >= off) ? s[t - off] : 0;
        __syncthreads();
        s[t] += a;
        __syncthreads();
    }
    if (i < N_NODES) tmp[i] = s[t];
    if (t == SCAN_BLK - 1) partial[blockIdx.x] = s[t];
}

__global__ void k_scan2(int* partial) {
    __shared__ int s[SCAN_BLK];
    int t = threadIdx.x;
    int v = (t < NBLK_SCAN) ? partial[t] : 0;
    s[t] = v;
    __syncthreads();
    for (int off = 1; off < SCAN_BLK; off <<= 1) {
        int a = (t >= off) ? s[t - off] : 0;
        __syncthreads();
        s[t] += a;
        __syncthreads();
    }
    if (t < NBLK_SCAN) partial[t] = s[t] - v;   // exclusive
}

__global__ void k_scan3(const int* __restrict__ tmp, const int* __restrict__ counts,
                        const int* __restrict__ partial, int* __restrict__ offsets) {
    int i = blockIdx.x * 256 + threadIdx.x;
    if (i < N_NODES) offsets[i] = tmp[i] - counts[i] + partial[i >> 8];
    if (i == 0) offsets[N_NODES] = EP;
}

__global__ void k_fill(const int* __restrict__ ei, const int* __restrict__ offsets,
                       int* __restrict__ cursor, int* __restrict__ edge_src) {
    int i = blockIdx.x * 256 + threadIdx.x;
    if (i >= EP) return;
    int s, d;
    if (i < N_EDGES) { s = ei[i]; d = ei[N_EDGES + i]; }
    else             { s = d = i - N_EDGES; }
    int pos = offsets[d] + atomicAdd(&cursor[d], 1);
    edge_src[pos] = s;
}

// ---------------- generic 64-col tile GEMM + fused attention-logit epilogue -----
// C[n, 0:64] = act(A[n, 0:KDIM] @ B[KDIM,64] + bias); optionally al_s/al_d = C . weff
// Used for: embedding (A=x, KDIM=128, no relu) and per-layer mix (A=U, KDIM=256, relu).
template<int KDIM, bool RELU, bool ATT>
__global__ __launch_bounds__(256) void k_gemm(const float* __restrict__ A,
                                              const float* __restrict__ B,
                                              const float* __restrict__ bias,
                                              const float* __restrict__ weff_s,
                                              const float* __restrict__ weff_d,
                                              float* __restrict__ hout,
                                              float* __restrict__ al_s,
                                              float* __restrict__ al_d) {
    __shared__ float smem[2 * NT * KP];      // aT | bs, reused as pp_s | pp_d in epilogue
    float* aT = smem;                        // [k][node]
    float* bs = smem + NT * KP;              // [k][col]
    int t = threadIdx.x;
    int n0 = blockIdx.x * NT;
    int w = t >> 6, l = t & 63;
    int tn = (w * 4 + (l >> 4)) * 4;         // node base
    int tc = (l & 15) * 4;                   // col base

    float4 a0 = {0,0,0,0}, a1 = {0,0,0,0}, a2 = {0,0,0,0}, a3 = {0,0,0,0};
    for (int kc = 0; kc < KDIM; kc += NT) {
        if (kc) __syncthreads();             // drain previous chunk's reads
        {   // stage A chunk transposed
            int r = t >> 2, s = t & 3;
            int rg = n0 + r; if (rg >= N_NODES) rg = N_NODES - 1;   // clamp (x has N rows)
            #pragma unroll
            for (int i = 0; i < 4; i++) {
                int q0 = (i * 4 + s) * 4;
                float4 v = *(const float4*)&A[(size_t)rg * KDIM + kc + q0];
                aT[(q0 + 0) * KP + r] = v.x;
                aT[(q0 + 1) * KP + r] = v.y;
                aT[(q0 + 2) * KP + r] = v.z;
                aT[(q0 + 3) * KP + r] = v.w;
            }
        }
        // stage B chunk [64k][64c]
        #pragma unroll
        for (int i = 0; i < 4; i++) {
            int idx = i * 256 + t;
            int k = idx >> 4, cq = (idx & 15) * 4;
            *(float4*)&bs[k * KP + cq] = *(const float4*)&B[(size_t)(kc + k) * HID + cq];
        }
        __syncthreads();
        for (int k = 0; k < NT; k++) {
            float4 hn = *(const float4*)&aT[k * KP + tn];
            float4 wc = *(const float4*)&bs[k * KP + tc];
            a0.x += hn.x * wc.x; a0.y += hn.x * wc.y; a0.z += hn.x * wc.z; a0.w += hn.x * wc.w;
            a1.x += hn.y * wc.x; a1.y += hn.y * wc.y; a1.z += hn.y * wc.z; a1.w += hn.y * wc.w;
            a2.x += hn.z * wc.x; a2.y += hn.z * wc.y; a2.z += hn.z * wc.z; a2.w += hn.z * wc.w;
            a3.x += hn.w * wc.x; a3.y += hn.w * wc.y; a3.z += hn.w * wc.z; a3.w += hn.w * wc.w;
        }
    }
    float4 bv = *(const float4*)&bias[tc];
    a0.x += bv.x; a0.y += bv.y; a0.z += bv.z; a0.w += bv.w;
    a1.x += bv.x; a1.y += bv.y; a1.z += bv.z; a1.w += bv.w;
    a2.x += bv.x; a2.y += bv.y; a2.z += bv.z; a2.w += bv.w;
    a3.x += bv.x; a3.y += bv.y; a3.z += bv.z; a3.w += bv.w;
    if (RELU) {
        a0.x = fmaxf(a0.x, 0.f); a0.y = fmaxf(a0.y, 0.f); a0.z = fmaxf(a0.z, 0.f); a0.w = fmaxf(a0.w, 0.f);
        a1.x = fmaxf(a1.x, 0.f); a1.y = fmaxf(a1.y, 0.f); a1.z = fmaxf(a1.z, 0.f); a1.w = fmaxf(a1.w, 0.f);
        a2.x = fmaxf(a2.x, 0.f); a2.y = fmaxf(a2.y, 0.f); a2.z = fmaxf(a2.z, 0.f); a2.w = fmaxf(a2.w, 0.f);
        a3.x = fmaxf(a3.x, 0.f); a3.y = fmaxf(a3.y, 0.f); a3.z = fmaxf(a3.z, 0.f); a3.w = fmaxf(a3.w, 0.f);
    }
    *(float4*)&hout[(size_t)(n0 + tn + 0) * HID + tc] = a0;
    *(float4*)&hout[(size_t)(n0 + tn + 1) * HID + tc] = a1;
    *(float4*)&hout[(size_t)(n0 + tn + 2) * HID + tc] = a2;
    *(float4*)&hout[(size_t)(n0 + tn + 3) * HID + tc] = a3;

    if (ATT) {
        // attention logits for the consuming layer: al[n,h] = hout[n,:] . weff[h,:]
        float4 ws4[HEADS], wd4[HEADS];
        #pragma unroll
        for (int hh = 0; hh < HEADS; hh++) {
            ws4[hh] = *(const float4*)&weff_s[hh * HID + tc];
            wd4[hh] = *(const float4*)&weff_d[hh * HID + tc];
        }
        __syncthreads();                     // done with staged GEMM LDS; overlay pp
        float* pps = smem;                   // [node][h][17] : node stride 68
        float* ppd = smem + NT * KP;
        int tcI = l & 15;
        float4 rows[4] = {a0, a1, a2, a3};
        #pragma unroll
        for (int q = 0; q < 4; q++) {
            #pragma unroll
            for (int hh = 0; hh < HEADS; hh++) {
                float ps = rows[q].x * ws4[hh].x + rows[q].y * ws4[hh].y +
                           rows[q].z * ws4[hh].z + rows[q].w * ws4[hh].w;
                float pd = rows[q].x * wd4[hh].x + rows[q].y * wd4[hh].y +
                           rows[q].z * wd4[hh].z + rows[q].w * wd4[hh].w;
                pps[(tn + q) * 68 + hh * 17 + tcI] = ps;
                ppd[(tn + q) * 68 + hh * 17 + tcI] = pd;
            }
        }
        __syncthreads();
        int node = t >> 2, hh = t & 3;       // 256 threads = 64 nodes x 4 heads
        float s1 = 0.f, s2 = 0.f;
        #pragma unroll
        for (int jj = 0; jj < 16; jj++) {
            s1 += pps[node * 68 + hh * 17 + jj];
            s2 += ppd[node * 68 + hh * 17 + jj];
        }
        al_s[(size_t)(n0 + node) * HEADS + hh] = s1;
        al_d[(size_t)(n0 + node) * HEADS + hh] = s2;
    }
}

__device__ __forceinline__ float lrelu(float v) { return v > 0.f ? v : NEG * v; }

// ---------------- fused softmax + h-space aggregate: ONE WAVE PER DST -----------
// U[dst, h*64+k] = sum_e alpha[e,h] * h[src_e, k]   (W applied afterwards by k_gemm)
__global__ void k_agg(const int* __restrict__ offsets, const int* __restrict__ edge_src,
                      const float* __restrict__ al_s, const float* __restrict__ al_d,
                      const float* __restrict__ h, float* __restrict__ U) {
    __shared__ float evb[4][HEADS * EVS];   // per wave: per-head alpha stash
    __shared__ int   sb[4][CAP];            // per wave: src idx stash
    int t  = threadIdx.x;
    int w  = t >> 6;
    int l  = t & 63;
    int hd = l >> 4;
    int j  = l & 15;
    int d  = blockIdx.x * 4 + w;

    int start = __builtin_amdgcn_readfirstlane(offsets[d]);
    int end   = __builtin_amdgcn_readfirstlane(offsets[d + 1]);
    int deg   = end - start;
    float al_dd = al_d[d * HEADS + hd];

    // phase 1: per-lane online softmax over strided edges; stash src + ev
    float m = -INFINITY, ssum = 0.f;
    for (int i = start + j; i < end; i += 16) {
        int s = edge_src[i];
        int slot = i - start;
        if (hd == 0 && slot < CAP) sb[w][slot] = s;
        float ev = lrelu(al_s[s * HEADS + hd] + al_dd);
        if (slot < CAP) evb[w][hd * EVS + slot] = ev;
        float nm = fmaxf(m, ev);
        ssum = ssum * __expf(m - nm) + __expf(ev - nm);
        m = nm;
    }
    float M = m;
    for (int o = 8; o > 0; o >>= 1) M = fmaxf(M, __shfl_xor(M, o));
    float S = ssum * __expf(m - M);
    for (int o = 8; o > 0; o >>= 1) S += __shfl_xor(S, o);
    float inv = 1.f / (S + 1e-16f);
    int stop = deg < CAP ? deg : CAP;
    for (int slot = j; slot < stop; slot += 16)
        evb[w][hd * EVS + slot] = __expf(evb[w][hd * EVS + slot] - M) * inv;

    // phase 2: alpha-weighted gather of h rows (256 B each), 8-deep pipelined
    // to keep more gather misses in flight (fabric-BW bound: target >4.5 TB/s)
    int hoff = j * 4;
    float4 acc = {0.f, 0.f, 0.f, 0.f};
    if (deg <= CAP) {
        float4 b1 = {0,0,0,0}, b2 = {0,0,0,0}, b3 = {0,0,0,0};
        int slot = 0;
        for (; slot + 8 <= deg; slot += 8) {
            int s0 = sb[w][slot],     s1 = sb[w][slot + 1];
            int s2 = sb[w][slot + 2], s3 = sb[w][slot + 3];
            int s4 = sb[w][slot + 4], s5 = sb[w][slot + 5];
            int s6 = sb[w][slot + 6], s7 = sb[w][slot + 7];
            float w0 = evb[w][hd * EVS + slot];
            float w1 = evb[w][hd * EVS + slot + 1];
            float w2 = evb[w][hd * EVS + slot + 2];
            float w3 = evb[w][hd * EVS + slot + 3];
            float w4 = evb[w][hd * EVS + slot + 4];
            float w5 = evb[w][hd * EVS + slot + 5];
            float w6 = evb[w][hd * EVS + slot + 6];
            float w7 = evb[w][hd * EVS + slot + 7];
            float4 h0 = *(const float4*)&h[(size_t)s0 * HID + hoff];
            float4 h1 = *(const float4*)&h[(size_t)s1 * HID + hoff];
            float4 h2 = *(const float4*)&h[(size_t)s2 * HID + hoff];
            float4 h3 = *(const float4*)&h[(size_t)s3 * HID + hoff];
            float4 h4 = *(const float4*)&h[(size_t)s4 * HID + hoff];
            float4 h5 = *(const float4*)&h[(size_t)s5 * HID + hoff];
            float4 h6 = *(const float4*)&h[(size_t)s6 * HID + hoff];
            float4 h7 = *(const float4*)&h[(size_t)s7 * HID + hoff];
            acc.x += w0 * h0.x; acc.y += w0 * h0.y; acc.z += w0 * h0.z; acc.w += w0 * h0.w;
            b1.x  += w1 * h1.x; b1.y  += w1 * h1.y; b1.z  += w1 * h1.z; b1.w  += w1 * h1.w;
            b2.x  += w2 * h2.x; b2.y  += w2 * h2.y; b2.z  += w2 * h2.z; b2.w  += w2 * h2.w;
            b3.x  += w3 * h3.x; b3.y  += w3 * h3.y; b3.z  += w3 * h3.z; b3.w  += w3 * h3.w;
            acc.x += w4 * h4.x; acc.y += w4 * h4.y; acc.z += w4 * h4.z; acc.w += w4 * h4.w;
            b1.x  += w5 * h5.x; b1.y  += w5 * h5.y; b1.z  += w5 * h5.z; b1.w  += w5 * h5.w;
            b2.x  += w6 * h6.x; b2.y  += w6 * h6.y; b2.z  += w6 * h6.z; b2.w  += w6 * h6.w;
            b3.x  += w7 * h7.x; b3.y  += w7 * h7.y; b3.z  += w7 * h7.z; b3.w  += w7 * h7.w;
        }
        for (; slot + 4 <= deg; slot += 4) {
            int s0 = sb[w][slot],     s1 = sb[w][slot + 1];
            int s2 = sb[w][slot + 2], s3 = sb[w][slot + 3];
            float w0 = evb[w][hd * EVS + slot];
            float w1 = evb[w][hd * EVS + slot + 1];
            float w2 = evb[w][hd * EVS + slot + 2];
            float w3 = evb[w][hd * EVS + slot + 3];
            float4 h0 = *(const float4*)&h[(size_t)s0 * HID + hoff];
            float4 h1 = *(const float4*)&h[(size_t)s1 * HID + hoff];
            float4 h2 = *(const float4*)&h[(size_t)s2 * HID + hoff];
            float4 h3 = *(const float4*)&h[(size_t)s3 * HID + hoff];
            acc.x += w0 * h0.x; acc.y += w0 * h0.y; acc.z += w0 * h0.z; acc.w += w0 * h0.w;
            b1.x  += w1 * h1.x; b1.y  += w1 * h1.y; b1.z  += w1 * h1.z; b1.w  += w1 * h1.w;
            b2.x  += w2 * h2.x; b2.y  += w2 * h2.y; b2.z  += w2 * h2.z; b2.w  += w2 * h2.w;
            b3.x  += w3 * h3.x; b3.y  += w3 * h3.y; b3.z  += w3 * h3.z; b3.w  += w3 * h3.w;
        }
        for (; slot < deg; slot++) {
            int s0 = sb[w][slot];
            float w0 = evb[w][hd * EVS + slot];
            float4 h0 = *(const float4*)&h[(size_t)s0 * HID + hoff];
            acc.x += w0 * h0.x; acc.y += w0 * h0.y; acc.z += w0 * h0.z; acc.w += w0 * h0.w;
        }
        acc.x += b1.x + b2.x + b3.x;
        acc.y += b1.y + b2.y + b3.y;
        acc.z += b1.z + b2.z + b3.z;
        acc.w += b1.w + b2.w + b3.w;
    } else {
        for (int i = start; i < end; i++) {
            int s = __builtin_amdgcn_readfirstlane(edge_src[i]);
            float ev = lrelu(al_s[s * HEADS + hd] + al_dd);
            float alpha = __expf(ev - M) * inv;
            float4 hr = *(const float4*)&h[(size_t)s * HID + hoff];
            acc.x += alpha * hr.x; acc.y += alpha * hr.y;
            acc.z += alpha * hr.z; acc.w += alpha * hr.w;
        }
    }
    // lane l = hd*16+j holds U[d, hd*64 + j*4 .. +3] == U[d, l*4 .. +3]
    *(float4*)&U[(size_t)d * ZD + l * 4] = acc;
}

// ---------------- global mean pool (batch is sorted; parallel over nodes) -------
// 256 threads = 4 node-lanes x 64 features; each thread walks a 16-node run.
__global__ __launch_bounds__(256) void k_pool(const float* __restrict__ h,
                                              const int* __restrict__ batch,
                                              float* __restrict__ pool,
                                              float* __restrict__ pool_cnt) {
    int t = threadIdx.x;
    int f  = t & 63;               // feature (wave = one node-lane, coalesced rows)
    int nl = t >> 6;               // node-lane 0..3
    int n0 = blockIdx.x * 64 + nl * 16;
    if (n0 >= N_NODES) return;
    int n1 = n0 + 16;
    if (n1 > N_NODES) n1 = N_NODES;
    int curg = batch[n0];
    float acc = 0.f;
    int cnt = 0;
    for (int n = n0; n < n1; n++) {
        int g = batch[n];
        if (g != curg) {
            atomicAdd(&pool[curg * HID + f], acc);
            if (f == 0) atomicAdd(&pool_cnt[curg], (float)cnt);
            acc = 0.f; cnt = 0; curg = g;
        }
        acc += h[(size_t)n * HID + f];
        cnt++;
    }
    atomicAdd(&pool[curg * HID + f], acc);
    if (f == 0) atomicAdd(&pool_cnt[curg], (float)cnt);
}

// ---------------- final FC: out = hg @ W_fc + b_fc (float4) ----------------
__global__ void k_fc(const float* __restrict__ pool, const float* __restrict__ pool_cnt,
                     const float* __restrict__ W_fc, const float* __restrict__ b_fc,
                     float* __restrict__ out) {
    __shared__ float hg[G_B * HID];
    int t = threadIdx.x;
    for (int i = t; i < G_B * HID; i += 256)
        hg[i] = pool[i] / fmaxf(pool_cnt[i / HID], 1.f);
    __syncthreads();
    int o4 = blockIdx.x * 256 + t;
    if (o4 >= OUT_F / 4) return;
    int o = o4 * 4;
    float4 acc[G_B];
    float4 bo = *(const float4*)&b_fc[o];
    #pragma unroll
    for (int g = 0; g < G_B; g++) acc[g] = bo;
    #pragma unroll 4
    for (int k = 0; k < HID; k++) {
        float4 wv = *(const float4*)&W_fc[(size_t)k * OUT_F + o];
        #pragma unroll
        for (int g = 0; g < G_B; g++) {
            float hv = hg[g * HID + k];
            acc[g].x += hv * wv.x; acc[g].y += hv * wv.y;
            acc[g].z += hv * wv.z; acc[g].w += hv * wv.w;
        }
    }
    #pragma unroll
    for (int g = 0; g < G_B; g++) *(float4*)&out[(size_t)g * OUT_F + o] = acc[g];
}

extern "C" void kernel_launch(void* const* d_in, const int* in_sizes, int n_in,
                              void* d_out, int out_size, void* d_ws, size_t ws_size,
                              hipStream_t stream) {
    const float* x       = (const float*)d_in[0];
    const int*   ei      = (const int*)d_in[1];
    // d_in[2] edge_attr: unused by the reference forward
    const int*   batch   = (const int*)d_in[3];
    const float* W_emb   = (const float*)d_in[4];
    const float* b_emb   = (const float*)d_in[5];
    const float* W_gat   = (const float*)d_in[6];
    const float* att_src = (const float*)d_in[7];
    const float* att_dst = (const float*)d_in[8];
    const float* b_gat   = (const float*)d_in[9];
    const float* W_fc    = (const float*)d_in[10];
    const float* b_fc    = (const float*)d_in[11];
    float* out = (float*)d_out;

    char* p = (char*)d_ws;
    auto alloc = [&](size_t bytes) -> void* {
        void* r = (void*)p;
        p += (bytes + 255) & ~(size_t)255;
        return r;
    };
    float* h        = (float*)alloc((size_t)NPAD * HID * 4);
    float* U        = (float*)alloc((size_t)NPAD * ZD * 4);
    float* al_s     = (float*)alloc((size_t)NPAD * HEADS * 4);
    float* al_d     = (float*)alloc((size_t)NPAD * HEADS * 4);
    int*   counts   = (int*)alloc((size_t)N_NODES * 4);
    int*   offsets  = (int*)alloc((size_t)(N_NODES + 1) * 4);
    int*   cursor   = (int*)alloc((size_t)N_NODES * 4);
    int*   tmp      = (int*)alloc((size_t)N_NODES * 4);
    int*   partial  = (int*)alloc((size_t)SCAN_BLK * 4);
    int*   edge_src = (int*)alloc((size_t)EP * 4);
    float* pool     = (float*)alloc((size_t)G_B * HID * 4);
    float* pool_cnt = (float*)alloc((size_t)G_B * 4);
    float* Wstk     = (float*)alloc((size_t)3 * ZD * HID * 4);
    float* weff_s   = (float*)alloc((size_t)3 * HEADS * HID * 4);
    float* weff_d   = (float*)alloc((size_t)3 * HEADS * HID * 4);

    // init + weight prep + CSR build (once per launch; reused by all 3 layers)
    k_init <<<NBLK_SCAN, 256, 0, stream>>>(counts, cursor, pool, pool_cnt,
                                           W_gat, att_src, att_dst,
                                           Wstk, weff_s, weff_d);
    k_count<<<(N_EDGES + 255) / 256, 256, 0, stream>>>(ei, counts);
    k_scan1<<<NBLK_SCAN, SCAN_BLK, 0, stream>>>(counts, tmp, partial);
    k_scan2<<<1, SCAN_BLK, 0, stream>>>(partial);
    k_scan3<<<NBLK_SCAN, 256, 0, stream>>>(tmp, counts, partial, offsets);
    k_fill <<<(EP + 255) / 256, 256, 0, stream>>>(ei, offsets, cursor, edge_src);

    // node embedding + layer-0 attention logits
    k_gemm<IN_F, false, true><<<NPAD / NT, 256, 0, stream>>>(
        x, W_emb, b_emb, weff_s, weff_d, h, al_s, al_d);

    // 3 GAT layers: aggregate in h-space, then mix with Wstk (+ next layer's logits)
    k_agg<<<N_NODES / 4, 256, 0, stream>>>(offsets, edge_src, al_s, al_d, h, U);
    k_gemm<ZD, true, true><<<NPAD / NT, 256, 0, stream>>>(
        U, Wstk, b_gat, weff_s + ZD, weff_d + ZD, h, al_s, al_d);

    k_agg<<<N_NODES / 4, 256, 0, stream>>>(offsets, edge_src, al_s, al_d, h, U);
    k_gemm<ZD, true, true><<<NPAD / NT, 256, 0, stream>>>(
        U, Wstk + (size_t)ZD * HID, b_gat + HID, weff_s + 2 * ZD, weff_d + 2 * ZD,
        h, al_s, al_d);

    k_agg<<<N_NODES / 4, 256, 0, stream>>>(offsets, edge_src, al_s, al_d, h, U);
    k_gemm<ZD, true, false><<<NPAD / NT, 256, 0, stream>>>(
        U, Wstk + (size_t)2 * ZD * HID, b_gat + 2 * HID, weff_s, weff_d,
        h, al_s, al_d);

    // pooling + FC
    k_pool<<<(N_NODES + 63) / 64, 256, 0, stream>>>(h, batch, pool, pool_cnt);
    k_fc  <<<(OUT_F / 4 + 255) / 256, 256, 0, stream>>>(pool, pool_cnt, W_fc, b_fc, out);
}

// Round 4
// 540.279 us; speedup vs baseline: 1.1005x; 1.1005x over previous
//
#include <hip/hip_runtime.h>
#include <math.h>

#define N_NODES 50000
#define NPAD 50048               // 64 * 782, padded node count for tiled GEMMs
#define N_EDGES 500000
#define EP (N_EDGES + N_NODES)   // 550000
#define IN_F 128
#define HID 64
#define HEADS 4
#define ZD (HEADS * HID)         // 256
#define G_B 16
#define OUT_F 326000
#define NEG 0.2f
#define SCAN_BLK 256
#define NBLK_SCAN ((N_NODES + SCAN_BLK - 1) / SCAN_BLK)   // 196
#define CAP 64                   // LDS-stash cap per dst
#define EVS 72                   // per-head LDS stride
#define NT 64                    // node tile for GEMM kernels
#define KP 68                    // padded k-row stride (mult of 4 for b128)

// ---------------- init + weight prep (merged: both trivially parallel) ----------
// Wstk[l][(h*64+k)][f] = 0.25 * W_gat[l][k][h*64+f]   (so h_next = relu(U@Wstk + b))
// weff_s[l][h][i] = sum_f W_gat[l][i][h*64+f] * att_src[l][h][f]   (al_s = h . weff_s)
__global__ void k_init(int* counts, int* cursor, float* pool, float* pool_cnt,
                       const float* __restrict__ W_gat, const float* __restrict__ att_src,
                       const float* __restrict__ att_dst, float* __restrict__ Wstk,
                       float* __restrict__ weff_s, float* __restrict__ weff_d) {
    int idx = blockIdx.x * 256 + threadIdx.x;
    if (idx < N_NODES) { counts[idx] = 1; cursor[idx] = 0; }
    if (idx < G_B * HID) pool[idx] = 0.f;
    if (idx < G_B) pool_cnt[idx] = 0.f;
    if (idx < 3 * ZD * HID) {
        int l = idx / (ZD * HID);
        int rem = idx - l * (ZD * HID);
        int hk = rem >> 6;            // 0..255  (h*64 + k)
        int f = rem & 63;
        int hh = hk >> 6, k = hk & 63;
        Wstk[idx] = 0.25f * W_gat[(size_t)l * HID * ZD + (size_t)k * ZD + hh * HID + f];
    }
    if (idx < 3 * HEADS * HID) {
        int l = idx / (HEADS * HID);
        int rem = idx - l * (HEADS * HID);
        int hh = rem >> 6, i = rem & 63;
        const float* Wl = W_gat + (size_t)l * HID * ZD;
        const float* as = att_src + l * HEADS * HID + hh * HID;
        const float* ad = att_dst + l * HEADS * HID + hh * HID;
        float ss = 0.f, sd = 0.f;
        for (int f = 0; f < HID; f++) {
            float wv = Wl[(size_t)i * ZD + hh * HID + f];
            ss += wv * as[f];
            sd += wv * ad[f];
        }
        weff_s[idx] = ss;
        weff_d[idx] = sd;
    }
}

__global__ void k_count(const int* __restrict__ ei, int* __restrict__ counts) {
    int i = blockIdx.x * 256 + threadIdx.x;
    if (i < N_EDGES) atomicAdd(&counts[ei[N_EDGES + i]], 1);
}

__global__ void k_scan1(const int* __restrict__ counts, int* __restrict__ tmp,
                        int* __restrict__ partial) {
    __shared__ int s[SCAN_BLK];
    int t = threadIdx.x;
    int i = blockIdx.x * SCAN_BLK + t;
    int v = (i < N_NODES) ? counts[i] : 0;
    s[t] = v;
    __syncthreads();
    for (int off = 1; off < SCAN_BLK; off <<= 1) {
        int a = (t >= off) ? s[t - off] : 0;
        __syncthreads();
        s[t] += a;
        __syncthreads();
    }
    if (i < N_NODES) tmp[i] = s[t];
    if (t == SCAN_BLK - 1) partial[blockIdx.x] = s[t];
}

__global__ void k_scan2(int* partial) {
    __shared__ int s[SCAN_BLK];
    int t = threadIdx.x;
    int v = (t < NBLK_SCAN) ? partial[t] : 0;
    s[t] = v;
    __syncthreads();
    for (int off = 1; off < SCAN_BLK; off <<= 1) {
        int a = (t >= off) ? s[t - off] : 0;
        __syncthreads();
        s[t] += a;
        __syncthreads();
    }
    if (t < NBLK_SCAN) partial[t] = s[t] - v;   // exclusive
}

__global__ void k_scan3(const int* __restrict__ tmp, const int* __restrict__ counts,
                        const int* __restrict__ partial, int* __restrict__ offsets) {
    int i = blockIdx.x * 256 + threadIdx.x;
    if (i < N_NODES) offsets[i] = tmp[i] - counts[i] + partial[i >> 8];
    if (i == 0) offsets[N_NODES] = EP;
}

__global__ void k_fill(const int* __restrict__ ei, const int* __restrict__ offsets,
                       int* __restrict__ cursor, int* __restrict__ edge_src) {
    int i = blockIdx.x * 256 + threadIdx.x;
    if (i >= EP) return;
    int s, d;
    if (i < N_EDGES) { s = ei[i]; d = ei[N_EDGES + i]; }
    else             { s = d = i - N_EDGES; }
    int pos = offsets[d] + atomicAdd(&cursor[d], 1);
    edge_src[pos] = s;
}

// ---------------- generic 64-col tile GEMM + fused attention-logit epilogue -----
// C[n, 0:64] = act(A[n, 0:KDIM] @ B[KDIM,64] + bias); optionally al_s/al_d = C . weff
// Used for: embedding (A=x, KDIM=128, no relu) and per-layer mix (A=U, KDIM=256, relu).
template<int KDIM, bool RELU, bool ATT>
__global__ __launch_bounds__(256) void k_gemm(const float* __restrict__ A,
                                              const float* __restrict__ B,
                                              const float* __restrict__ bias,
                                              const float* __restrict__ weff_s,
                                              const float* __restrict__ weff_d,
                                              float* __restrict__ hout,
                                              float* __restrict__ al_s,
                                              float* __restrict__ al_d) {
    __shared__ float smem[2 * NT * KP];      // aT | bs, reused as pp_s | pp_d in epilogue
    float* aT = smem;                        // [k][node]
    float* bs = smem + NT * KP;              // [k][col]
    int t = threadIdx.x;
    int n0 = blockIdx.x * NT;
    int w = t >> 6, l = t & 63;
    int tn = (w * 4 + (l >> 4)) * 4;         // node base
    int tc = (l & 15) * 4;                   // col base

    float4 a0 = {0,0,0,0}, a1 = {0,0,0,0}, a2 = {0,0,0,0}, a3 = {0,0,0,0};
    for (int kc = 0; kc < KDIM; kc += NT) {
        if (kc) __syncthreads();             // drain previous chunk's reads
        {   // stage A chunk transposed
            int r = t >> 2, s = t & 3;
            int rg = n0 + r; if (rg >= N_NODES) rg = N_NODES - 1;   // clamp (x has N rows)
            #pragma unroll
            for (int i = 0; i < 4; i++) {
                int q0 = (i * 4 + s) * 4;
                float4 v = *(const float4*)&A[(size_t)rg * KDIM + kc + q0];
                aT[(q0 + 0) * KP + r] = v.x;
                aT[(q0 + 1) * KP + r] = v.y;
                aT[(q0 + 2) * KP + r] = v.z;
                aT[(q0 + 3) * KP + r] = v.w;
            }
        }
        // stage B chunk [64k][64c]
        #pragma unroll
        for (int i = 0; i < 4; i++) {
            int idx = i * 256 + t;
            int k = idx >> 4, cq = (idx & 15) * 4;
            *(float4*)&bs[k * KP + cq] = *(const float4*)&B[(size_t)(kc + k) * HID + cq];
        }
        __syncthreads();
        for (int k = 0; k < NT; k++) {
            float4 hn = *(const float4*)&aT[k * KP + tn];
            float4 wc = *(const float4*)&bs[k * KP + tc];
            a0.x += hn.x * wc.x; a0.y += hn.x * wc.y; a0.z += hn.x * wc.z; a0.w += hn.x * wc.w;
            a1.x += hn.y * wc.x; a1.y += hn.y * wc.y; a1.z += hn.y * wc.z; a1.w += hn.y * wc.w;
            a2.x += hn.z * wc.x; a2.y += hn.z * wc.y; a2.z += hn.z * wc.z; a2.w += hn.z * wc.w;
            a3.x += hn.w * wc.x; a3.y += hn.w * wc.y; a3.z += hn.w * wc.z; a3.w += hn.w * wc.w;
        }
    }
    float4 bv = *(const float4*)&bias[tc];
    a0.x += bv.x; a0.y += bv.y; a0.z += bv.z; a0.w += bv.w;
    a1.x += bv.x; a1.y += bv.y; a1.z += bv.z; a1.w += bv.w;
    a2.x += bv.x; a2.y += bv.y; a2.z += bv.z; a2.w += bv.w;
    a3.x += bv.x; a3.y += bv.y; a3.z += bv.z; a3.w += bv.w;
    if (RELU) {
        a0.x = fmaxf(a0.x, 0.f); a0.y = fmaxf(a0.y, 0.f); a0.z = fmaxf(a0.z, 0.f); a0.w = fmaxf(a0.w, 0.f);
        a1.x = fmaxf(a1.x, 0.f); a1.y = fmaxf(a1.y, 0.f); a1.z = fmaxf(a1.z, 0.f); a1.w = fmaxf(a1.w, 0.f);
        a2.x = fmaxf(a2.x, 0.f); a2.y = fmaxf(a2.y, 0.f); a2.z = fmaxf(a2.z, 0.f); a2.w = fmaxf(a2.w, 0.f);
        a3.x = fmaxf(a3.x, 0.f); a3.y = fmaxf(a3.y, 0.f); a3.z = fmaxf(a3.z, 0.f); a3.w = fmaxf(a3.w, 0.f);
    }
    *(float4*)&hout[(size_t)(n0 + tn + 0) * HID + tc] = a0;
    *(float4*)&hout[(size_t)(n0 + tn + 1) * HID + tc] = a1;
    *(float4*)&hout[(size_t)(n0 + tn + 2) * HID + tc] = a2;
    *(float4*)&hout[(size_t)(n0 + tn + 3) * HID + tc] = a3;

    if (ATT) {
        // attention logits for the consuming layer: al[n,h] = hout[n,:] . weff[h,:]
        float4 ws4[HEADS], wd4[HEADS];
        #pragma unroll
        for (int hh = 0; hh < HEADS; hh++) {
            ws4[hh] = *(const float4*)&weff_s[hh * HID + tc];
            wd4[hh] = *(const float4*)&weff_d[hh * HID + tc];
        }
        __syncthreads();                     // done with staged GEMM LDS; overlay pp
        float* pps = smem;                   // [node][h][17] : node stride 68
        float* ppd = smem + NT * KP;
        int tcI = l & 15;
        float4 rows[4] = {a0, a1, a2, a3};
        #pragma unroll
        for (int q = 0; q < 4; q++) {
            #pragma unroll
            for (int hh = 0; hh < HEADS; hh++) {
                float ps = rows[q].x * ws4[hh].x + rows[q].y * ws4[hh].y +
                           rows[q].z * ws4[hh].z + rows[q].w * ws4[hh].w;
                float pd = rows[q].x * wd4[hh].x + rows[q].y * wd4[hh].y +
                           rows[q].z * wd4[hh].z + rows[q].w * wd4[hh].w;
                pps[(tn + q) * 68 + hh * 17 + tcI] = ps;
                ppd[(tn + q) * 68 + hh * 17 + tcI] = pd;
            }
        }
        __syncthreads();
        int node = t >> 2, hh = t & 3;       // 256 threads = 64 nodes x 4 heads
        float s1 = 0.f, s2 = 0.f;
        #pragma unroll
        for (int jj = 0; jj < 16; jj++) {
            s1 += pps[node * 68 + hh * 17 + jj];
            s2 += ppd[node * 68 + hh * 17 + jj];
        }
        al_s[(size_t)(n0 + node) * HEADS + hh] = s1;
        al_d[(size_t)(n0 + node) * HEADS + hh] = s2;
    }
}

__device__ __forceinline__ float lrelu(float v) { return v > 0.f ? v : NEG * v; }

// ---------------- fused softmax + h-space aggregate: ONE WAVE PER DST -----------
// U[dst, h*64+k] = sum_e alpha[e,h] * h[src_e, k]   (W applied afterwards by k_gemm)
__global__ void k_agg(const int* __restrict__ offsets, const int* __restrict__ edge_src,
                      const float* __restrict__ al_s, const float* __restrict__ al_d,
                      const float* __restrict__ h, float* __restrict__ U) {
    __shared__ float evb[4][HEADS * EVS];   // per wave: per-head alpha stash
    __shared__ int   sb[4][CAP];            // per wave: src idx stash
    int t  = threadIdx.x;
    int w  = t >> 6;
    int l  = t & 63;
    int hd = l >> 4;
    int j  = l & 15;
    int d  = blockIdx.x * 4 + w;

    int start = __builtin_amdgcn_readfirstlane(offsets[d]);
    int end   = __builtin_amdgcn_readfirstlane(offsets[d + 1]);
    int deg   = end - start;
    float al_dd = al_d[d * HEADS + hd];

    // phase 1: per-lane online softmax over strided edges; stash src + ev
    float m = -INFINITY, ssum = 0.f;
    for (int i = start + j; i < end; i += 16) {
        int s = edge_src[i];
        int slot = i - start;
        if (hd == 0 && slot < CAP) sb[w][slot] = s;
        float ev = lrelu(al_s[s * HEADS + hd] + al_dd);
        if (slot < CAP) evb[w][hd * EVS + slot] = ev;
        float nm = fmaxf(m, ev);
        ssum = ssum * __expf(m - nm) + __expf(ev - nm);
        m = nm;
    }
    float M = m;
    for (int o = 8; o > 0; o >>= 1) M = fmaxf(M, __shfl_xor(M, o));
    float S = ssum * __expf(m - M);
    for (int o = 8; o > 0; o >>= 1) S += __shfl_xor(S, o);
    float inv = 1.f / (S + 1e-16f);
    int stop = deg < CAP ? deg : CAP;
    for (int slot = j; slot < stop; slot += 16)
        evb[w][hd * EVS + slot] = __expf(evb[w][hd * EVS + slot] - M) * inv;

    // phase 2: alpha-weighted gather of h rows (256 B each), 8-deep pipelined
    // to keep more gather misses in flight (fabric-BW bound)
    int hoff = j * 4;
    float4 acc = {0.f, 0.f, 0.f, 0.f};
    if (deg <= CAP) {
        float4 b1 = {0,0,0,0}, b2 = {0,0,0,0}, b3 = {0,0,0,0};
        int slot = 0;
        for (; slot + 8 <= deg; slot += 8) {
            int s0 = sb[w][slot],     s1 = sb[w][slot + 1];
            int s2 = sb[w][slot + 2], s3 = sb[w][slot + 3];
            int s4 = sb[w][slot + 4], s5 = sb[w][slot + 5];
            int s6 = sb[w][slot + 6], s7 = sb[w][slot + 7];
            float w0 = evb[w][hd * EVS + slot];
            float w1 = evb[w][hd * EVS + slot + 1];
            float w2 = evb[w][hd * EVS + slot + 2];
            float w3 = evb[w][hd * EVS + slot + 3];
            float w4 = evb[w][hd * EVS + slot + 4];
            float w5 = evb[w][hd * EVS + slot + 5];
            float w6 = evb[w][hd * EVS + slot + 6];
            float w7 = evb[w][hd * EVS + slot + 7];
            float4 h0 = *(const float4*)&h[(size_t)s0 * HID + hoff];
            float4 h1 = *(const float4*)&h[(size_t)s1 * HID + hoff];
            float4 h2 = *(const float4*)&h[(size_t)s2 * HID + hoff];
            float4 h3 = *(const float4*)&h[(size_t)s3 * HID + hoff];
            float4 h4 = *(const float4*)&h[(size_t)s4 * HID + hoff];
            float4 h5 = *(const float4*)&h[(size_t)s5 * HID + hoff];
            float4 h6 = *(const float4*)&h[(size_t)s6 * HID + hoff];
            float4 h7 = *(const float4*)&h[(size_t)s7 * HID + hoff];
            acc.x += w0 * h0.x; acc.y += w0 * h0.y; acc.z += w0 * h0.z; acc.w += w0 * h0.w;
            b1.x  += w1 * h1.x; b1.y  += w1 * h1.y; b1.z  += w1 * h1.z; b1.w  += w1 * h1.w;
            b2.x  += w2 * h2.x; b2.y  += w2 * h2.y; b2.z  += w2 * h2.z; b2.w  += w2 * h2.w;
            b3.x  += w3 * h3.x; b3.y  += w3 * h3.y; b3.z  += w3 * h3.z; b3.w  += w3 * h3.w;
            acc.x += w4 * h4.x; acc.y += w4 * h4.y; acc.z += w4 * h4.z; acc.w += w4 * h4.w;
            b1.x  += w5 * h5.x; b1.y  += w5 * h5.y; b1.z  += w5 * h5.z; b1.w  += w5 * h5.w;
            b2.x  += w6 * h6.x; b2.y  += w6 * h6.y; b2.z  += w6 * h6.z; b2.w  += w6 * h6.w;
            b3.x  += w7 * h7.x; b3.y  += w7 * h7.y; b3.z  += w7 * h7.z; b3.w  += w7 * h7.w;
        }
        for (; slot + 4 <= deg; slot += 4) {
            int s0 = sb[w][slot],     s1 = sb[w][slot + 1];
            int s2 = sb[w][slot + 2], s3 = sb[w][slot + 3];
            float w0 = evb[w][hd * EVS + slot];
            float w1 = evb[w][hd * EVS + slot + 1];
            float w2 = evb[w][hd * EVS + slot + 2];
            float w3 = evb[w][hd * EVS + slot + 3];
            float4 h0 = *(const float4*)&h[(size_t)s0 * HID + hoff];
            float4 h1 = *(const float4*)&h[(size_t)s1 * HID + hoff];
            float4 h2 = *(const float4*)&h[(size_t)s2 * HID + hoff];
            float4 h3 = *(const float4*)&h[(size_t)s3 * HID + hoff];
            acc.x += w0 * h0.x; acc.y += w0 * h0.y; acc.z += w0 * h0.z; acc.w += w0 * h0.w;
            b1.x  += w1 * h1.x; b1.y  += w1 * h1.y; b1.z  += w1 * h1.z; b1.w  += w1 * h1.w;
            b2.x  += w2 * h2.x; b2.y  += w2 * h2.y; b2.z  += w2 * h2.z; b2.w  += w2 * h2.w;
            b3.x  += w3 * h3.x; b3.y  += w3 * h3.y; b3.z  += w3 * h3.z; b3.w  += w3 * h3.w;
        }
        for (; slot < deg; slot++) {
            int s0 = sb[w][slot];
            float w0 = evb[w][hd * EVS + slot];
            float4 h0 = *(const float4*)&h[(size_t)s0 * HID + hoff];
            acc.x += w0 * h0.x; acc.y += w0 * h0.y; acc.z += w0 * h0.z; acc.w += w0 * h0.w;
        }
        acc.x += b1.x + b2.x + b3.x;
        acc.y += b1.y + b2.y + b3.y;
        acc.z += b1.z + b2.z + b3.z;
        acc.w += b1.w + b2.w + b3.w;
    } else {
        for (int i = start; i < end; i++) {
            int s = __builtin_amdgcn_readfirstlane(edge_src[i]);
            float ev = lrelu(al_s[s * HEADS + hd] + al_dd);
            float alpha = __expf(ev - M) * inv;
            float4 hr = *(const float4*)&h[(size_t)s * HID + hoff];
            acc.x += alpha * hr.x; acc.y += alpha * hr.y;
            acc.z += alpha * hr.z; acc.w += alpha * hr.w;
        }
    }
    // lane l = hd*16+j holds U[d, hd*64 + j*4 .. +3] == U[d, l*4 .. +3]
    *(float4*)&U[(size_t)d * ZD + l * 4] = acc;
}

// ---------------- global mean pool (batch is sorted; parallel over nodes) -------
// 256 threads = 4 node-lanes x 64 features; each thread walks a 16-node run.
__global__ __launch_bounds__(256) void k_pool(const float* __restrict__ h,
                                              const int* __restrict__ batch,
                                              float* __restrict__ pool,
                                              float* __restrict__ pool_cnt) {
    int t = threadIdx.x;
    int f  = t & 63;               // feature (wave = one node-lane, coalesced rows)
    int nl = t >> 6;               // node-lane 0..3
    int n0 = blockIdx.x * 64 + nl * 16;
    if (n0 >= N_NODES) return;
    int n1 = n0 + 16;
    if (n1 > N_NODES) n1 = N_NODES;
    int curg = batch[n0];
    float acc = 0.f;
    int cnt = 0;
    for (int n = n0; n < n1; n++) {
        int g = batch[n];
        if (g != curg) {
            atomicAdd(&pool[curg * HID + f], acc);
            if (f == 0) atomicAdd(&pool_cnt[curg], (float)cnt);
            acc = 0.f; cnt = 0; curg = g;
        }
        acc += h[(size_t)n * HID + f];
        cnt++;
    }
    atomicAdd(&pool[curg * HID + f], acc);
    if (f == 0) atomicAdd(&pool_cnt[curg], (float)cnt);
}

// ---------------- final FC: out = hg @ W_fc + b_fc ----------------
// Grid-limited (~1.25 waves/SIMD) -> VGPRs are free: __launch_bounds__(256,1)
// releases the register cap (round-3's unroll spilled acc[16] at the 64-VGPR
// 8-wave target). Chunk-of-8 prefetch keeps 8 independent 1KB loads in flight.
__global__ __launch_bounds__(256, 1) void k_fc(const float* __restrict__ pool,
                                               const float* __restrict__ pool_cnt,
                                               const float* __restrict__ W_fc,
                                               const float* __restrict__ b_fc,
                                               float* __restrict__ out) {
    __shared__ float hg[G_B * HID];
    int t = threadIdx.x;
    for (int i = t; i < G_B * HID; i += 256)
        hg[i] = pool[i] / fmaxf(pool_cnt[i / HID], 1.f);
    __syncthreads();
    int o4 = blockIdx.x * 256 + t;
    if (o4 >= OUT_F / 4) return;
    int o = o4 * 4;
    float4 acc[G_B];
    float4 bo = *(const float4*)&b_fc[o];
    #pragma unroll
    for (int g = 0; g < G_B; g++) acc[g] = bo;
    for (int kc = 0; kc < HID; kc += 8) {
        float4 wv[8];
        #pragma unroll
        for (int u = 0; u < 8; u++)
            wv[u] = *(const float4*)&W_fc[(size_t)(kc + u) * OUT_F + o];
        #pragma unroll
        for (int u = 0; u < 8; u++) {
            #pragma unroll
            for (int g = 0; g < G_B; g++) {
                float hv = hg[g * HID + kc + u];
                acc[g].x += hv * wv[u].x; acc[g].y += hv * wv[u].y;
                acc[g].z += hv * wv[u].z; acc[g].w += hv * wv[u].w;
            }
        }
    }
    #pragma unroll
    for (int g = 0; g < G_B; g++) *(float4*)&out[(size_t)g * OUT_F + o] = acc[g];
}

extern "C" void kernel_launch(void* const* d_in, const int* in_sizes, int n_in,
                              void* d_out, int out_size, void* d_ws, size_t ws_size,
                              hipStream_t stream) {
    const float* x       = (const float*)d_in[0];
    const int*   ei      = (const int*)d_in[1];
    // d_in[2] edge_attr: unused by the reference forward
    const int*   batch   = (const int*)d_in[3];
    const float* W_emb   = (const float*)d_in[4];
    const float* b_emb   = (const float*)d_in[5];
    const float* W_gat   = (const float*)d_in[6];
    const float* att_src = (const float*)d_in[7];
    const float* att_dst = (const float*)d_in[8];
    const float* b_gat   = (const float*)d_in[9];
    const float* W_fc    = (const float*)d_in[10];
    const float* b_fc    = (const float*)d_in[11];
    float* out = (float*)d_out;

    char* p = (char*)d_ws;
    auto alloc = [&](size_t bytes) -> void* {
        void* r = (void*)p;
        p += (bytes + 255) & ~(size_t)255;
        return r;
    };
    float* h        = (float*)alloc((size_t)NPAD * HID * 4);
    float* U        = (float*)alloc((size_t)NPAD * ZD * 4);
    float* al_s     = (float*)alloc((size_t)NPAD * HEADS * 4);
    float* al_d     = (float*)alloc((size_t)NPAD * HEADS * 4);
    int*   counts   = (int*)alloc((size_t)N_NODES * 4);
    int*   offsets  = (int*)alloc((size_t)(N_NODES + 1) * 4);
    int*   cursor   = (int*)alloc((size_t)N_NODES * 4);
    int*   tmp      = (int*)alloc((size_t)N_NODES * 4);
    int*   partial  = (int*)alloc((size_t)SCAN_BLK * 4);
    int*   edge_src = (int*)alloc((size_t)EP * 4);
    float* pool     = (float*)alloc((size_t)G_B * HID * 4);
    float* pool_cnt = (float*)alloc((size_t)G_B * 4);
    float* Wstk     = (float*)alloc((size_t)3 * ZD * HID * 4);
    float* weff_s   = (float*)alloc((size_t)3 * HEADS * HID * 4);
    float* weff_d   = (float*)alloc((size_t)3 * HEADS * HID * 4);

    // init + weight prep + CSR build (once per launch; reused by all 3 layers)
    k_init <<<NBLK_SCAN, 256, 0, stream>>>(counts, cursor, pool, pool_cnt,
                                           W_gat, att_src, att_dst,
                                           Wstk, weff_s, weff_d);
    k_count<<<(N_EDGES + 255) / 256, 256, 0, stream>>>(ei, counts);
    k_scan1<<<NBLK_SCAN, SCAN_BLK, 0, stream>>>(counts, tmp, partial);
    k_scan2<<<1, SCAN_BLK, 0, stream>>>(partial);
    k_scan3<<<NBLK_SCAN, 256, 0, stream>>>(tmp, counts, partial, offsets);
    k_fill <<<(EP + 255) / 256, 256, 0, stream>>>(ei, offsets, cursor, edge_src);

    // node embedding + layer-0 attention logits
    k_gemm<IN_F, false, true><<<NPAD / NT, 256, 0, stream>>>(
        x, W_emb, b_emb, weff_s, weff_d, h, al_s, al_d);

    // 3 GAT layers: aggregate in h-space, then mix with Wstk (+ next layer's logits)
    k_agg<<<N_NODES / 4, 256, 0, stream>>>(offsets, edge_src, al_s, al_d, h, U);
    k_gemm<ZD, true, true><<<NPAD / NT, 256, 0, stream>>>(
        U, Wstk, b_gat, weff_s + ZD, weff_d + ZD, h, al_s, al_d);

    k_agg<<<N_NODES / 4, 256, 0, stream>>>(offsets, edge_src, al_s, al_d, h, U);
    k_gemm<ZD, true, true><<<NPAD / NT, 256, 0, stream>>>(
        U, Wstk + (size_t)ZD * HID, b_gat + HID, weff_s + 2 * ZD, weff_d + 2 * ZD,
        h, al_s, al_d);

    k_agg<<<N_NODES / 4, 256, 0, stream>>>(offsets, edge_src, al_s, al_d, h, U);
    k_gemm<ZD, true, false><<<NPAD / NT, 256, 0, stream>>>(
        U, Wstk + (size_t)2 * ZD * HID, b_gat + 2 * HID, weff_s, weff_d,
        h, al_s, al_d);

    // pooling + FC
    k_pool<<<(N_NODES + 63) / 64, 256, 0, stream>>>(h, batch, pool, pool_cnt);
    k_fc  <<<(OUT_F / 4 + 255) / 256, 256, 0, stream>>>(pool, pool_cnt, W_fc, b_fc, out);
}

// Round 5
// 522.049 us; speedup vs baseline: 1.1389x; 1.0349x over previous
//
#include <hip/hip_runtime.h>
#include <math.h>

#define N_NODES 50000
#define NPAD 50048               // 64 * 782, padded node count for tiled GEMMs
#define N_EDGES 500000
#define EP (N_EDGES + N_NODES)   // 550000
#define IN_F 128
#define HID 64
#define HEADS 4
#define ZD (HEADS * HID)         // 256
#define G_B 16
#define OUT_F 326000
#define NEG 0.2f
#define SCAN_BLK 256
#define NBLK_SCAN ((N_NODES + SCAN_BLK - 1) / SCAN_BLK)   // 196
#define CAP 64                   // LDS-stash cap per dst
#define EVS 72                   // per-head LDS stride
#define NT 64                    // node tile for GEMM kernels
#define KP 68                    // padded k-row stride (mult of 4 for b128)
#define FC_GS 4                  // graphs per k_fc block (grid x4 for occupancy)

// ---------------- init + weight prep (merged: both trivially parallel) ----------
// Wstk[l][(h*64+k)][f] = 0.25 * W_gat[l][k][h*64+f]   (so h_next = relu(U@Wstk + b))
// weff_s[l][h][i] = sum_f W_gat[l][i][h*64+f] * att_src[l][h][f]   (al_s = h . weff_s)
__global__ void k_init(int* counts, int* cursor, float* pool, float* pool_cnt,
                       const float* __restrict__ W_gat, const float* __restrict__ att_src,
                       const float* __restrict__ att_dst, float* __restrict__ Wstk,
                       float* __restrict__ weff_s, float* __restrict__ weff_d) {
    int idx = blockIdx.x * 256 + threadIdx.x;
    if (idx < N_NODES) { counts[idx] = 1; cursor[idx] = 0; }
    if (idx < G_B * HID) pool[idx] = 0.f;
    if (idx < G_B) pool_cnt[idx] = 0.f;
    if (idx < 3 * ZD * HID) {
        int l = idx / (ZD * HID);
        int rem = idx - l * (ZD * HID);
        int hk = rem >> 6;            // 0..255  (h*64 + k)
        int f = rem & 63;
        int hh = hk >> 6, k = hk & 63;
        Wstk[idx] = 0.25f * W_gat[(size_t)l * HID * ZD + (size_t)k * ZD + hh * HID + f];
    }
    if (idx < 3 * HEADS * HID) {
        int l = idx / (HEADS * HID);
        int rem = idx - l * (HEADS * HID);
        int hh = rem >> 6, i = rem & 63;
        const float* Wl = W_gat + (size_t)l * HID * ZD;
        const float* as = att_src + l * HEADS * HID + hh * HID;
        const float* ad = att_dst + l * HEADS * HID + hh * HID;
        float ss = 0.f, sd = 0.f;
        for (int f = 0; f < HID; f++) {
            float wv = Wl[(size_t)i * ZD + hh * HID + f];
            ss += wv * as[f];
            sd += wv * ad[f];
        }
        weff_s[idx] = ss;
        weff_d[idx] = sd;
    }
}

__global__ void k_count(const int* __restrict__ ei, int* __restrict__ counts) {
    int i = blockIdx.x * 256 + threadIdx.x;
    if (i < N_EDGES) atomicAdd(&counts[ei[N_EDGES + i]], 1);
}

__global__ void k_scan1(const int* __restrict__ counts, int* __restrict__ tmp,
                        int* __restrict__ partial) {
    __shared__ int s[SCAN_BLK];
    int t = threadIdx.x;
    int i = blockIdx.x * SCAN_BLK + t;
    int v = (i < N_NODES) ? counts[i] : 0;
    s[t] = v;
    __syncthreads();
    for (int off = 1; off < SCAN_BLK; off <<= 1) {
        int a = (t >= off) ? s[t - off] : 0;
        __syncthreads();
        s[t] += a;
        __syncthreads();
    }
    if (i < N_NODES) tmp[i] = s[t];
    if (t == SCAN_BLK - 1) partial[blockIdx.x] = s[t];
}

__global__ void k_scan2(int* partial) {
    __shared__ int s[SCAN_BLK];
    int t = threadIdx.x;
    int v = (t < NBLK_SCAN) ? partial[t] : 0;
    s[t] = v;
    __syncthreads();
    for (int off = 1; off < SCAN_BLK; off <<= 1) {
        int a = (t >= off) ? s[t - off] : 0;
        __syncthreads();
        s[t] += a;
        __syncthreads();
    }
    if (t < NBLK_SCAN) partial[t] = s[t] - v;   // exclusive
}

__global__ void k_scan3(const int* __restrict__ tmp, const int* __restrict__ counts,
                        const int* __restrict__ partial, int* __restrict__ offsets) {
    int i = blockIdx.x * 256 + threadIdx.x;
    if (i < N_NODES) offsets[i] = tmp[i] - counts[i] + partial[i >> 8];
    if (i == 0) offsets[N_NODES] = EP;
}

__global__ void k_fill(const int* __restrict__ ei, const int* __restrict__ offsets,
                       int* __restrict__ cursor, int* __restrict__ edge_src) {
    int i = blockIdx.x * 256 + threadIdx.x;
    if (i >= EP) return;
    int s, d;
    if (i < N_EDGES) { s = ei[i]; d = ei[N_EDGES + i]; }
    else             { s = d = i - N_EDGES; }
    int pos = offsets[d] + atomicAdd(&cursor[d], 1);
    edge_src[pos] = s;
}

// ---------------- generic 64-col tile GEMM + fused attention-logit epilogue -----
// C[n, 0:64] = act(A[n, 0:KDIM] @ B[KDIM,64] + bias); optionally al_s/al_d = C . weff
// Used for: embedding (A=x, KDIM=128, no relu) and per-layer mix (A=U, KDIM=256, relu).
template<int KDIM, bool RELU, bool ATT>
__global__ __launch_bounds__(256) void k_gemm(const float* __restrict__ A,
                                              const float* __restrict__ B,
                                              const float* __restrict__ bias,
                                              const float* __restrict__ weff_s,
                                              const float* __restrict__ weff_d,
                                              float* __restrict__ hout,
                                              float* __restrict__ al_s,
                                              float* __restrict__ al_d) {
    __shared__ float smem[2 * NT * KP];      // aT | bs, reused as pp_s | pp_d in epilogue
    float* aT = smem;                        // [k][node]
    float* bs = smem + NT * KP;              // [k][col]
    int t = threadIdx.x;
    int n0 = blockIdx.x * NT;
    int w = t >> 6, l = t & 63;
    int tn = (w * 4 + (l >> 4)) * 4;         // node base
    int tc = (l & 15) * 4;                   // col base

    float4 a0 = {0,0,0,0}, a1 = {0,0,0,0}, a2 = {0,0,0,0}, a3 = {0,0,0,0};
    for (int kc = 0; kc < KDIM; kc += NT) {
        if (kc) __syncthreads();             // drain previous chunk's reads
        {   // stage A chunk transposed
            int r = t >> 2, s = t & 3;
            int rg = n0 + r; if (rg >= N_NODES) rg = N_NODES - 1;   // clamp (x has N rows)
            #pragma unroll
            for (int i = 0; i < 4; i++) {
                int q0 = (i * 4 + s) * 4;
                float4 v = *(const float4*)&A[(size_t)rg * KDIM + kc + q0];
                aT[(q0 + 0) * KP + r] = v.x;
                aT[(q0 + 1) * KP + r] = v.y;
                aT[(q0 + 2) * KP + r] = v.z;
                aT[(q0 + 3) * KP + r] = v.w;
            }
        }
        // stage B chunk [64k][64c]
        #pragma unroll
        for (int i = 0; i < 4; i++) {
            int idx = i * 256 + t;
            int k = idx >> 4, cq = (idx & 15) * 4;
            *(float4*)&bs[k * KP + cq] = *(const float4*)&B[(size_t)(kc + k) * HID + cq];
        }
        __syncthreads();
        for (int k = 0; k < NT; k++) {
            float4 hn = *(const float4*)&aT[k * KP + tn];
            float4 wc = *(const float4*)&bs[k * KP + tc];
            a0.x += hn.x * wc.x; a0.y += hn.x * wc.y; a0.z += hn.x * wc.z; a0.w += hn.x * wc.w;
            a1.x += hn.y * wc.x; a1.y += hn.y * wc.y; a1.z += hn.y * wc.z; a1.w += hn.y * wc.w;
            a2.x += hn.z * wc.x; a2.y += hn.z * wc.y; a2.z += hn.z * wc.z; a2.w += hn.z * wc.w;
            a3.x += hn.w * wc.x; a3.y += hn.w * wc.y; a3.z += hn.w * wc.z; a3.w += hn.w * wc.w;
        }
    }
    float4 bv = *(const float4*)&bias[tc];
    a0.x += bv.x; a0.y += bv.y; a0.z += bv.z; a0.w += bv.w;
    a1.x += bv.x; a1.y += bv.y; a1.z += bv.z; a1.w += bv.w;
    a2.x += bv.x; a2.y += bv.y; a2.z += bv.z; a2.w += bv.w;
    a3.x += bv.x; a3.y += bv.y; a3.z += bv.z; a3.w += bv.w;
    if (RELU) {
        a0.x = fmaxf(a0.x, 0.f); a0.y = fmaxf(a0.y, 0.f); a0.z = fmaxf(a0.z, 0.f); a0.w = fmaxf(a0.w, 0.f);
        a1.x = fmaxf(a1.x, 0.f); a1.y = fmaxf(a1.y, 0.f); a1.z = fmaxf(a1.z, 0.f); a1.w = fmaxf(a1.w, 0.f);
        a2.x = fmaxf(a2.x, 0.f); a2.y = fmaxf(a2.y, 0.f); a2.z = fmaxf(a2.z, 0.f); a2.w = fmaxf(a2.w, 0.f);
        a3.x = fmaxf(a3.x, 0.f); a3.y = fmaxf(a3.y, 0.f); a3.z = fmaxf(a3.z, 0.f); a3.w = fmaxf(a3.w, 0.f);
    }
    *(float4*)&hout[(size_t)(n0 + tn + 0) * HID + tc] = a0;
    *(float4*)&hout[(size_t)(n0 + tn + 1) * HID + tc] = a1;
    *(float4*)&hout[(size_t)(n0 + tn + 2) * HID + tc] = a2;
    *(float4*)&hout[(size_t)(n0 + tn + 3) * HID + tc] = a3;

    if (ATT) {
        // attention logits for the consuming layer: al[n,h] = hout[n,:] . weff[h,:]
        float4 ws4[HEADS], wd4[HEADS];
        #pragma unroll
        for (int hh = 0; hh < HEADS; hh++) {
            ws4[hh] = *(const float4*)&weff_s[hh * HID + tc];
            wd4[hh] = *(const float4*)&weff_d[hh * HID + tc];
        }
        __syncthreads();                     // done with staged GEMM LDS; overlay pp
        float* pps = smem;                   // [node][h][17] : node stride 68
        float* ppd = smem + NT * KP;
        int tcI = l & 15;
        float4 rows[4] = {a0, a1, a2, a3};
        #pragma unroll
        for (int q = 0; q < 4; q++) {
            #pragma unroll
            for (int hh = 0; hh < HEADS; hh++) {
                float ps = rows[q].x * ws4[hh].x + rows[q].y * ws4[hh].y +
                           rows[q].z * ws4[hh].z + rows[q].w * ws4[hh].w;
                float pd = rows[q].x * wd4[hh].x + rows[q].y * wd4[hh].y +
                           rows[q].z * wd4[hh].z + rows[q].w * wd4[hh].w;
                pps[(tn + q) * 68 + hh * 17 + tcI] = ps;
                ppd[(tn + q) * 68 + hh * 17 + tcI] = pd;
            }
        }
        __syncthreads();
        int node = t >> 2, hh = t & 3;       // 256 threads = 64 nodes x 4 heads
        float s1 = 0.f, s2 = 0.f;
        #pragma unroll
        for (int jj = 0; jj < 16; jj++) {
            s1 += pps[node * 68 + hh * 17 + jj];
            s2 += ppd[node * 68 + hh * 17 + jj];
        }
        al_s[(size_t)(n0 + node) * HEADS + hh] = s1;
        al_d[(size_t)(n0 + node) * HEADS + hh] = s2;
    }
}

__device__ __forceinline__ float lrelu(float v) { return v > 0.f ? v : NEG * v; }

// ---------------- fused softmax + h-space aggregate: ONE WAVE PER DST -----------
// U[dst, h*64+k] = sum_e alpha[e,h] * h[src_e, k]   (W applied afterwards by k_gemm)
__global__ void k_agg(const int* __restrict__ offsets, const int* __restrict__ edge_src,
                      const float* __restrict__ al_s, const float* __restrict__ al_d,
                      const float* __restrict__ h, float* __restrict__ U) {
    __shared__ float evb[4][HEADS * EVS];   // per wave: per-head alpha stash
    __shared__ int   sb[4][CAP];            // per wave: src idx stash
    int t  = threadIdx.x;
    int w  = t >> 6;
    int l  = t & 63;
    int hd = l >> 4;
    int j  = l & 15;
    int d  = blockIdx.x * 4 + w;

    int start = __builtin_amdgcn_readfirstlane(offsets[d]);
    int end   = __builtin_amdgcn_readfirstlane(offsets[d + 1]);
    int deg   = end - start;
    float al_dd = al_d[d * HEADS + hd];

    // phase 1: per-lane online softmax over strided edges; stash src + ev
    float m = -INFINITY, ssum = 0.f;
    for (int i = start + j; i < end; i += 16) {
        int s = edge_src[i];
        int slot = i - start;
        if (hd == 0 && slot < CAP) sb[w][slot] = s;
        float ev = lrelu(al_s[s * HEADS + hd] + al_dd);
        if (slot < CAP) evb[w][hd * EVS + slot] = ev;
        float nm = fmaxf(m, ev);
        ssum = ssum * __expf(m - nm) + __expf(ev - nm);
        m = nm;
    }
    float M = m;
    for (int o = 8; o > 0; o >>= 1) M = fmaxf(M, __shfl_xor(M, o));
    float S = ssum * __expf(m - M);
    for (int o = 8; o > 0; o >>= 1) S += __shfl_xor(S, o);
    float inv = 1.f / (S + 1e-16f);
    int stop = deg < CAP ? deg : CAP;
    for (int slot = j; slot < stop; slot += 16)
        evb[w][hd * EVS + slot] = __expf(evb[w][hd * EVS + slot] - M) * inv;

    // phase 2: alpha-weighted gather of h rows (256 B each), 8-deep pipelined
    // to keep more gather misses in flight (fabric-BW bound)
    int hoff = j * 4;
    float4 acc = {0.f, 0.f, 0.f, 0.f};
    if (deg <= CAP) {
        float4 b1 = {0,0,0,0}, b2 = {0,0,0,0}, b3 = {0,0,0,0};
        int slot = 0;
        for (; slot + 8 <= deg; slot += 8) {
            int s0 = sb[w][slot],     s1 = sb[w][slot + 1];
            int s2 = sb[w][slot + 2], s3 = sb[w][slot + 3];
            int s4 = sb[w][slot + 4], s5 = sb[w][slot + 5];
            int s6 = sb[w][slot + 6], s7 = sb[w][slot + 7];
            float w0 = evb[w][hd * EVS + slot];
            float w1 = evb[w][hd * EVS + slot + 1];
            float w2 = evb[w][hd * EVS + slot + 2];
            float w3 = evb[w][hd * EVS + slot + 3];
            float w4 = evb[w][hd * EVS + slot + 4];
            float w5 = evb[w][hd * EVS + slot + 5];
            float w6 = evb[w][hd * EVS + slot + 6];
            float w7 = evb[w][hd * EVS + slot + 7];
            float4 h0 = *(const float4*)&h[(size_t)s0 * HID + hoff];
            float4 h1 = *(const float4*)&h[(size_t)s1 * HID + hoff];
            float4 h2 = *(const float4*)&h[(size_t)s2 * HID + hoff];
            float4 h3 = *(const float4*)&h[(size_t)s3 * HID + hoff];
            float4 h4 = *(const float4*)&h[(size_t)s4 * HID + hoff];
            float4 h5 = *(const float4*)&h[(size_t)s5 * HID + hoff];
            float4 h6 = *(const float4*)&h[(size_t)s6 * HID + hoff];
            float4 h7 = *(const float4*)&h[(size_t)s7 * HID + hoff];
            acc.x += w0 * h0.x; acc.y += w0 * h0.y; acc.z += w0 * h0.z; acc.w += w0 * h0.w;
            b1.x  += w1 * h1.x; b1.y  += w1 * h1.y; b1.z  += w1 * h1.z; b1.w  += w1 * h1.w;
            b2.x  += w2 * h2.x; b2.y  += w2 * h2.y; b2.z  += w2 * h2.z; b2.w  += w2 * h2.w;
            b3.x  += w3 * h3.x; b3.y  += w3 * h3.y; b3.z  += w3 * h3.z; b3.w  += w3 * h3.w;
            acc.x += w4 * h4.x; acc.y += w4 * h4.y; acc.z += w4 * h4.z; acc.w += w4 * h4.w;
            b1.x  += w5 * h5.x; b1.y  += w5 * h5.y; b1.z  += w5 * h5.z; b1.w  += w5 * h5.w;
            b2.x  += w6 * h6.x; b2.y  += w6 * h6.y; b2.z  += w6 * h6.z; b2.w  += w6 * h6.w;
            b3.x  += w7 * h7.x; b3.y  += w7 * h7.y; b3.z  += w7 * h7.z; b3.w  += w7 * h7.w;
        }
        for (; slot + 4 <= deg; slot += 4) {
            int s0 = sb[w][slot],     s1 = sb[w][slot + 1];
            int s2 = sb[w][slot + 2], s3 = sb[w][slot + 3];
            float w0 = evb[w][hd * EVS + slot];
            float w1 = evb[w][hd * EVS + slot + 1];
            float w2 = evb[w][hd * EVS + slot + 2];
            float w3 = evb[w][hd * EVS + slot + 3];
            float4 h0 = *(const float4*)&h[(size_t)s0 * HID + hoff];
            float4 h1 = *(const float4*)&h[(size_t)s1 * HID + hoff];
            float4 h2 = *(const float4*)&h[(size_t)s2 * HID + hoff];
            float4 h3 = *(const float4*)&h[(size_t)s3 * HID + hoff];
            acc.x += w0 * h0.x; acc.y += w0 * h0.y; acc.z += w0 * h0.z; acc.w += w0 * h0.w;
            b1.x  += w1 * h1.x; b1.y  += w1 * h1.y; b1.z  += w1 * h1.z; b1.w  += w1 * h1.w;
            b2.x  += w2 * h2.x; b2.y  += w2 * h2.y; b2.z  += w2 * h2.z; b2.w  += w2 * h2.w;
            b3.x  += w3 * h3.x; b3.y  += w3 * h3.y; b3.z  += w3 * h3.z; b3.w  += w3 * h3.w;
        }
        for (; slot < deg; slot++) {
            int s0 = sb[w][slot];
            float w0 = evb[w][hd * EVS + slot];
            float4 h0 = *(const float4*)&h[(size_t)s0 * HID + hoff];
            acc.x += w0 * h0.x; acc.y += w0 * h0.y; acc.z += w0 * h0.z; acc.w += w0 * h0.w;
        }
        acc.x += b1.x + b2.x + b3.x;
        acc.y += b1.y + b2.y + b3.y;
        acc.z += b1.z + b2.z + b3.z;
        acc.w += b1.w + b2.w + b3.w;
    } else {
        for (int i = start; i < end; i++) {
            int s = __builtin_amdgcn_readfirstlane(edge_src[i]);
            float ev = lrelu(al_s[s * HEADS + hd] + al_dd);
            float alpha = __expf(ev - M) * inv;
            float4 hr = *(const float4*)&h[(size_t)s * HID + hoff];
            acc.x += alpha * hr.x; acc.y += alpha * hr.y;
            acc.z += alpha * hr.z; acc.w += alpha * hr.w;
        }
    }
    // lane l = hd*16+j holds U[d, hd*64 + j*4 .. +3] == U[d, l*4 .. +3]
    *(float4*)&U[(size_t)d * ZD + l * 4] = acc;
}

// ---------------- global mean pool (batch is sorted; parallel over nodes) -------
// 256 threads = 4 node-lanes x 64 features; each thread walks a 16-node run.
__global__ __launch_bounds__(256) void k_pool(const float* __restrict__ h,
                                              const int* __restrict__ batch,
                                              float* __restrict__ pool,
                                              float* __restrict__ pool_cnt) {
    int t = threadIdx.x;
    int f  = t & 63;               // feature (wave = one node-lane, coalesced rows)
    int nl = t >> 6;               // node-lane 0..3
    int n0 = blockIdx.x * 64 + nl * 16;
    if (n0 >= N_NODES) return;
    int n1 = n0 + 16;
    if (n1 > N_NODES) n1 = N_NODES;
    int curg = batch[n0];
    float acc = 0.f;
    int cnt = 0;
    for (int n = n0; n < n1; n++) {
        int g = batch[n];
        if (g != curg) {
            atomicAdd(&pool[curg * HID + f], acc);
            if (f == 0) atomicAdd(&pool_cnt[curg], (float)cnt);
            acc = 0.f; cnt = 0; curg = g;
        }
        acc += h[(size_t)n * HID + f];
        cnt++;
    }
    atomicAdd(&pool[curg * HID + f], acc);
    if (f == 0) atomicAdd(&pool_cnt[curg], (float)cnt);
}

// ---------------- final FC: out = hg @ W_fc + b_fc ----------------
// Round-4 PMC: 319 blocks -> 1.25 waves/SIMD, Occupancy 7.4%, latency-bound at
// 0.69 TB/s. Fix: split the G dimension FC_GS-ways (grid x4 -> ~20 waves/CU);
// blocks 4b..4b+3 share one W_fc slice (L2/L3 reuse). acc shrinks to 4 float4,
// freeing VGPRs for a chunk-of-16 prefetch (16 independent 1KB loads in flight).
__global__ __launch_bounds__(256, 1) void k_fc(const float* __restrict__ pool,
                                               const float* __restrict__ pool_cnt,
                                               const float* __restrict__ W_fc,
                                               const float* __restrict__ b_fc,
                                               float* __restrict__ out) {
    __shared__ float hg[FC_GS * HID];
    int t = threadIdx.x;
    int bg = blockIdx.x & (FC_GS - 1);   // graph group (adjacent blocks share W_fc)
    int ob = blockIdx.x / FC_GS;         // output block
    int g0 = bg * (G_B / FC_GS);
    if (t < FC_GS * HID) {
        int g = g0 + (t >> 6), f = t & 63;
        hg[t] = pool[g * HID + f] / fmaxf(pool_cnt[g], 1.f);
    }
    __syncthreads();
    int o4 = ob * 256 + t;
    if (o4 >= OUT_F / 4) return;
    int o = o4 * 4;
    float4 acc[FC_GS];
    float4 bo = *(const float4*)&b_fc[o];
    #pragma unroll
    for (int g = 0; g < FC_GS; g++) acc[g] = bo;
    for (int kc = 0; kc < HID; kc += 16) {
        float4 wv[16];
        #pragma unroll
        for (int u = 0; u < 16; u++)
            wv[u] = *(const float4*)&W_fc[(size_t)(kc + u) * OUT_F + o];
        #pragma unroll
        for (int u = 0; u < 16; u++) {
            #pragma unroll
            for (int g = 0; g < FC_GS; g++) {
                float hv = hg[g * HID + kc + u];
                acc[g].x += hv * wv[u].x; acc[g].y += hv * wv[u].y;
                acc[g].z += hv * wv[u].z; acc[g].w += hv * wv[u].w;
            }
        }
    }
    #pragma unroll
    for (int g = 0; g < FC_GS; g++)
        *(float4*)&out[(size_t)(g0 + g) * OUT_F + o] = acc[g];
}

extern "C" void kernel_launch(void* const* d_in, const int* in_sizes, int n_in,
                              void* d_out, int out_size, void* d_ws, size_t ws_size,
                              hipStream_t stream) {
    const float* x       = (const float*)d_in[0];
    const int*   ei      = (const int*)d_in[1];
    // d_in[2] edge_attr: unused by the reference forward
    const int*   batch   = (const int*)d_in[3];
    const float* W_emb   = (const float*)d_in[4];
    const float* b_emb   = (const float*)d_in[5];
    const float* W_gat   = (const float*)d_in[6];
    const float* att_src = (const float*)d_in[7];
    const float* att_dst = (const float*)d_in[8];
    const float* b_gat   = (const float*)d_in[9];
    const float* W_fc    = (const float*)d_in[10];
    const float* b_fc    = (const float*)d_in[11];
    float* out = (float*)d_out;

    char* p = (char*)d_ws;
    auto alloc = [&](size_t bytes) -> void* {
        void* r = (void*)p;
        p += (bytes + 255) & ~(size_t)255;
        return r;
    };
    float* h        = (float*)alloc((size_t)NPAD * HID * 4);
    float* U        = (float*)alloc((size_t)NPAD * ZD * 4);
    float* al_s     = (float*)alloc((size_t)NPAD * HEADS * 4);
    float* al_d     = (float*)alloc((size_t)NPAD * HEADS * 4);
    int*   counts   = (int*)alloc((size_t)N_NODES * 4);
    int*   offsets  = (int*)alloc((size_t)(N_NODES + 1) * 4);
    int*   cursor   = (int*)alloc((size_t)N_NODES * 4);
    int*   tmp      = (int*)alloc((size_t)N_NODES * 4);
    int*   partial  = (int*)alloc((size_t)SCAN_BLK * 4);
    int*   edge_src = (int*)alloc((size_t)EP * 4);
    float* pool     = (float*)alloc((size_t)G_B * HID * 4);
    float* pool_cnt = (float*)alloc((size_t)G_B * 4);
    float* Wstk     = (float*)alloc((size_t)3 * ZD * HID * 4);
    float* weff_s   = (float*)alloc((size_t)3 * HEADS * HID * 4);
    float* weff_d   = (float*)alloc((size_t)3 * HEADS * HID * 4);

    // init + weight prep + CSR build (once per launch; reused by all 3 layers)
    k_init <<<NBLK_SCAN, 256, 0, stream>>>(counts, cursor, pool, pool_cnt,
                                           W_gat, att_src, att_dst,
                                           Wstk, weff_s, weff_d);
    k_count<<<(N_EDGES + 255) / 256, 256, 0, stream>>>(ei, counts);
    k_scan1<<<NBLK_SCAN, SCAN_BLK, 0, stream>>>(counts, tmp, partial);
    k_scan2<<<1, SCAN_BLK, 0, stream>>>(partial);
    k_scan3<<<NBLK_SCAN, 256, 0, stream>>>(tmp, counts, partial, offsets);
    k_fill <<<(EP + 255) / 256, 256, 0, stream>>>(ei, offsets, cursor, edge_src);

    // node embedding + layer-0 attention logits
    k_gemm<IN_F, false, true><<<NPAD / NT, 256, 0, stream>>>(
        x, W_emb, b_emb, weff_s, weff_d, h, al_s, al_d);

    // 3 GAT layers: aggregate in h-space, then mix with Wstk (+ next layer's logits)
    k_agg<<<N_NODES / 4, 256, 0, stream>>>(offsets, edge_src, al_s, al_d, h, U);
    k_gemm<ZD, true, true><<<NPAD / NT, 256, 0, stream>>>(
        U, Wstk, b_gat, weff_s + ZD, weff_d + ZD, h, al_s, al_d);

    k_agg<<<N_NODES / 4, 256, 0, stream>>>(offsets, edge_src, al_s, al_d, h, U);
    k_gemm<ZD, true, true><<<NPAD / NT, 256, 0, stream>>>(
        U, Wstk + (size_t)ZD * HID, b_gat + HID, weff_s + 2 * ZD, weff_d + 2 * ZD,
        h, al_s, al_d);

    k_agg<<<N_NODES / 4, 256, 0, stream>>>(offsets, edge_src, al_s, al_d, h, U);
    k_gemm<ZD, true, false><<<NPAD / NT, 256, 0, stream>>>(
        U, Wstk + (size_t)2 * ZD * HID, b_gat + 2 * HID, weff_s, weff_d,
        h, al_s, al_d);

    // pooling + FC
    k_pool<<<(N_NODES + 63) / 64, 256, 0, stream>>>(h, batch, pool, pool_cnt);
    k_fc  <<<((OUT_F / 4 + 255) / 256) * FC_GS, 256, 0, stream>>>(
        pool, pool_cnt, W_fc, b_fc, out);
}

// Round 6
// 510.852 us; speedup vs baseline: 1.1639x; 1.0219x over previous
//
#include <hip/hip_runtime.h>
#include <math.h>

#define N_NODES 50000
#define NPAD 50048               // 64 * 782, padded node count for tiled GEMMs
#define N_EDGES 500000
#define EP (N_EDGES + N_NODES)   // 550000
#define IN_F 128
#define HID 64
#define HEADS 4
#define ZD (HEADS * HID)         // 256
#define G_B 16
#define OUT_F 326000
#define NEG 0.2f
#define SCAN_BLK 256
#define NBLK_SCAN ((N_NODES + SCAN_BLK - 1) / SCAN_BLK)   // 196
#define CAP 64                   // LDS-stash cap per dst
#define EVS 72                   // per-head LDS stride
#define NT 64                    // node tile for GEMM kernels
#define KP 68                    // padded k-row stride (mult of 4 for b128)
#define FC_GS 4                  // graphs per k_fc block (grid x4 for occupancy)
#define FC_NOB ((OUT_F / 4 + 255) / 256)   // 319 output blocks

// ---------------- init + weight prep (merged: both trivially parallel) ----------
// Wstk[l][(h*64+k)][f] = 0.25 * W_gat[l][k][h*64+f]   (so h_next = relu(U@Wstk + b))
// weff_s[l][h][i] = sum_f W_gat[l][i][h*64+f] * att_src[l][h][f]   (al_s = h . weff_s)
__global__ void k_init(int* counts, int* cursor, float* pool, float* pool_cnt,
                       const float* __restrict__ W_gat, const float* __restrict__ att_src,
                       const float* __restrict__ att_dst, float* __restrict__ Wstk,
                       float* __restrict__ weff_s, float* __restrict__ weff_d) {
    int idx = blockIdx.x * 256 + threadIdx.x;
    if (idx < N_NODES) { counts[idx] = 1; cursor[idx] = 0; }
    if (idx < G_B * HID) pool[idx] = 0.f;
    if (idx < G_B) pool_cnt[idx] = 0.f;
    if (idx < 3 * ZD * HID) {
        int l = idx / (ZD * HID);
        int rem = idx - l * (ZD * HID);
        int hk = rem >> 6;            // 0..255  (h*64 + k)
        int f = rem & 63;
        int hh = hk >> 6, k = hk & 63;
        Wstk[idx] = 0.25f * W_gat[(size_t)l * HID * ZD + (size_t)k * ZD + hh * HID + f];
    }
    if (idx < 3 * HEADS * HID) {
        int l = idx / (HEADS * HID);
        int rem = idx - l * (HEADS * HID);
        int hh = rem >> 6, i = rem & 63;
        const float* Wl = W_gat + (size_t)l * HID * ZD;
        const float* as = att_src + l * HEADS * HID + hh * HID;
        const float* ad = att_dst + l * HEADS * HID + hh * HID;
        float ss = 0.f, sd = 0.f;
        for (int f = 0; f < HID; f++) {
            float wv = Wl[(size_t)i * ZD + hh * HID + f];
            ss += wv * as[f];
            sd += wv * ad[f];
        }
        weff_s[idx] = ss;
        weff_d[idx] = sd;
    }
}

__global__ void k_count(const int* __restrict__ ei, int* __restrict__ counts) {
    int i = blockIdx.x * 256 + threadIdx.x;
    if (i < N_EDGES) atomicAdd(&counts[ei[N_EDGES + i]], 1);
}

__global__ void k_scan1(const int* __restrict__ counts, int* __restrict__ tmp,
                        int* __restrict__ partial) {
    __shared__ int s[SCAN_BLK];
    int t = threadIdx.x;
    int i = blockIdx.x * SCAN_BLK + t;
    int v = (i < N_NODES) ? counts[i] : 0;
    s[t] = v;
    __syncthreads();
    for (int off = 1; off < SCAN_BLK; off <<= 1) {
        int a = (t >= off) ? s[t - off] : 0;
        __syncthreads();
        s[t] += a;
        __syncthreads();
    }
    if (i < N_NODES) tmp[i] = s[t];
    if (t == SCAN_BLK - 1) partial[blockIdx.x] = s[t];
}

__global__ void k_scan2(int* partial) {
    __shared__ int s[SCAN_BLK];
    int t = threadIdx.x;
    int v = (t < NBLK_SCAN) ? partial[t] : 0;
    s[t] = v;
    __syncthreads();
    for (int off = 1; off < SCAN_BLK; off <<= 1) {
        int a = (t >= off) ? s[t - off] : 0;
        __syncthreads();
        s[t] += a;
        __syncthreads();
    }
    if (t < NBLK_SCAN) partial[t] = s[t] - v;   // exclusive
}

__global__ void k_scan3(const int* __restrict__ tmp, const int* __restrict__ counts,
                        const int* __restrict__ partial, int* __restrict__ offsets) {
    int i = blockIdx.x * 256 + threadIdx.x;
    if (i < N_NODES) offsets[i] = tmp[i] - counts[i] + partial[i >> 8];
    if (i == 0) offsets[N_NODES] = EP;
}

__global__ void k_fill(const int* __restrict__ ei, const int* __restrict__ offsets,
                       int* __restrict__ cursor, int* __restrict__ edge_src) {
    int i = blockIdx.x * 256 + threadIdx.x;
    if (i >= EP) return;
    int s, d;
    if (i < N_EDGES) { s = ei[i]; d = ei[N_EDGES + i]; }
    else             { s = d = i - N_EDGES; }
    int pos = offsets[d] + atomicAdd(&cursor[d], 1);
    edge_src[pos] = s;
}

// ---------------- generic 64-col tile GEMM + fused attention-logit epilogue -----
// C[n, 0:64] = act(A[n, 0:KDIM] @ B[KDIM,64] + bias); optionally al_s/al_d = C . weff
// Used for: embedding (A=x, KDIM=128, no relu) and per-layer mix (A=U, KDIM=256, relu).
template<int KDIM, bool RELU, bool ATT>
__global__ __launch_bounds__(256) void k_gemm(const float* __restrict__ A,
                                              const float* __restrict__ B,
                                              const float* __restrict__ bias,
                                              const float* __restrict__ weff_s,
                                              const float* __restrict__ weff_d,
                                              float* __restrict__ hout,
                                              float* __restrict__ al_s,
                                              float* __restrict__ al_d) {
    __shared__ float smem[2 * NT * KP];      // aT | bs, reused as pp_s | pp_d in epilogue
    float* aT = smem;                        // [k][node]
    float* bs = smem + NT * KP;              // [k][col]
    int t = threadIdx.x;
    int n0 = blockIdx.x * NT;
    int w = t >> 6, l = t & 63;
    int tn = (w * 4 + (l >> 4)) * 4;         // node base
    int tc = (l & 15) * 4;                   // col base

    float4 a0 = {0,0,0,0}, a1 = {0,0,0,0}, a2 = {0,0,0,0}, a3 = {0,0,0,0};
    for (int kc = 0; kc < KDIM; kc += NT) {
        if (kc) __syncthreads();             // drain previous chunk's reads
        {   // stage A chunk transposed
            int r = t >> 2, s = t & 3;
            int rg = n0 + r; if (rg >= N_NODES) rg = N_NODES - 1;   // clamp (x has N rows)
            #pragma unroll
            for (int i = 0; i < 4; i++) {
                int q0 = (i * 4 + s) * 4;
                float4 v = *(const float4*)&A[(size_t)rg * KDIM + kc + q0];
                aT[(q0 + 0) * KP + r] = v.x;
                aT[(q0 + 1) * KP + r] = v.y;
                aT[(q0 + 2) * KP + r] = v.z;
                aT[(q0 + 3) * KP + r] = v.w;
            }
        }
        // stage B chunk [64k][64c]
        #pragma unroll
        for (int i = 0; i < 4; i++) {
            int idx = i * 256 + t;
            int k = idx >> 4, cq = (idx & 15) * 4;
            *(float4*)&bs[k * KP + cq] = *(const float4*)&B[(size_t)(kc + k) * HID + cq];
        }
        __syncthreads();
        for (int k = 0; k < NT; k++) {
            float4 hn = *(const float4*)&aT[k * KP + tn];
            float4 wc = *(const float4*)&bs[k * KP + tc];
            a0.x += hn.x * wc.x; a0.y += hn.x * wc.y; a0.z += hn.x * wc.z; a0.w += hn.x * wc.w;
            a1.x += hn.y * wc.x; a1.y += hn.y * wc.y; a1.z += hn.y * wc.z; a1.w += hn.y * wc.w;
            a2.x += hn.z * wc.x; a2.y += hn.z * wc.y; a2.z += hn.z * wc.z; a2.w += hn.z * wc.w;
            a3.x += hn.w * wc.x; a3.y += hn.w * wc.y; a3.z += hn.w * wc.z; a3.w += hn.w * wc.w;
        }
    }
    float4 bv = *(const float4*)&bias[tc];
    a0.x += bv.x; a0.y += bv.y; a0.z += bv.z; a0.w += bv.w;
    a1.x += bv.x; a1.y += bv.y; a1.z += bv.z; a1.w += bv.w;
    a2.x += bv.x; a2.y += bv.y; a2.z += bv.z; a2.w += bv.w;
    a3.x += bv.x; a3.y += bv.y; a3.z += bv.z; a3.w += bv.w;
    if (RELU) {
        a0.x = fmaxf(a0.x, 0.f); a0.y = fmaxf(a0.y, 0.f); a0.z = fmaxf(a0.z, 0.f); a0.w = fmaxf(a0.w, 0.f);
        a1.x = fmaxf(a1.x, 0.f); a1.y = fmaxf(a1.y, 0.f); a1.z = fmaxf(a1.z, 0.f); a1.w = fmaxf(a1.w, 0.f);
        a2.x = fmaxf(a2.x, 0.f); a2.y = fmaxf(a2.y, 0.f); a2.z = fmaxf(a2.z, 0.f); a2.w = fmaxf(a2.w, 0.f);
        a3.x = fmaxf(a3.x, 0.f); a3.y = fmaxf(a3.y, 0.f); a3.z = fmaxf(a3.z, 0.f); a3.w = fmaxf(a3.w, 0.f);
    }
    *(float4*)&hout[(size_t)(n0 + tn + 0) * HID + tc] = a0;
    *(float4*)&hout[(size_t)(n0 + tn + 1) * HID + tc] = a1;
    *(float4*)&hout[(size_t)(n0 + tn + 2) * HID + tc] = a2;
    *(float4*)&hout[(size_t)(n0 + tn + 3) * HID + tc] = a3;

    if (ATT) {
        // attention logits for the consuming layer: al[n,h] = hout[n,:] . weff[h,:]
        float4 ws4[HEADS], wd4[HEADS];
        #pragma unroll
        for (int hh = 0; hh < HEADS; hh++) {
            ws4[hh] = *(const float4*)&weff_s[hh * HID + tc];
            wd4[hh] = *(const float4*)&weff_d[hh * HID + tc];
        }
        __syncthreads();                     // done with staged GEMM LDS; overlay pp
        float* pps = smem;                   // [node][h][17] : node stride 68
        float* ppd = smem + NT * KP;
        int tcI = l & 15;
        float4 rows[4] = {a0, a1, a2, a3};
        #pragma unroll
        for (int q = 0; q < 4; q++) {
            #pragma unroll
            for (int hh = 0; hh < HEADS; hh++) {
                float ps = rows[q].x * ws4[hh].x + rows[q].y * ws4[hh].y +
                           rows[q].z * ws4[hh].z + rows[q].w * ws4[hh].w;
                float pd = rows[q].x * wd4[hh].x + rows[q].y * wd4[hh].y +
                           rows[q].z * wd4[hh].z + rows[q].w * wd4[hh].w;
                pps[(tn + q) * 68 + hh * 17 + tcI] = ps;
                ppd[(tn + q) * 68 + hh * 17 + tcI] = pd;
            }
        }
        __syncthreads();
        int node = t >> 2, hh = t & 3;       // 256 threads = 64 nodes x 4 heads
        float s1 = 0.f, s2 = 0.f;
        #pragma unroll
        for (int jj = 0; jj < 16; jj++) {
            s1 += pps[node * 68 + hh * 17 + jj];
            s2 += ppd[node * 68 + hh * 17 + jj];
        }
        al_s[(size_t)(n0 + node) * HEADS + hh] = s1;
        al_d[(size_t)(n0 + node) * HEADS + hh] = s2;
    }
}

__device__ __forceinline__ float lrelu(float v) { return v > 0.f ? v : NEG * v; }

// ---------------- fused softmax + h-space aggregate: ONE WAVE PER DST -----------
// U[dst, h*64+k] = sum_e alpha[e,h] * h[src_e, k]   (W applied afterwards by k_gemm)
__global__ void k_agg(const int* __restrict__ offsets, const int* __restrict__ edge_src,
                      const float* __restrict__ al_s, const float* __restrict__ al_d,
                      const float* __restrict__ h, float* __restrict__ U) {
    __shared__ float evb[4][HEADS * EVS];   // per wave: per-head alpha stash
    __shared__ int   sb[4][CAP];            // per wave: src idx stash
    int t  = threadIdx.x;
    int w  = t >> 6;
    int l  = t & 63;
    int hd = l >> 4;
    int j  = l & 15;
    int d  = blockIdx.x * 4 + w;

    int start = __builtin_amdgcn_readfirstlane(offsets[d]);
    int end   = __builtin_amdgcn_readfirstlane(offsets[d + 1]);
    int deg   = end - start;
    float al_dd = al_d[d * HEADS + hd];

    // phase 1: per-lane online softmax over strided edges; stash src + ev
    float m = -INFINITY, ssum = 0.f;
    for (int i = start + j; i < end; i += 16) {
        int s = edge_src[i];
        int slot = i - start;
        if (hd == 0 && slot < CAP) sb[w][slot] = s;
        float ev = lrelu(al_s[s * HEADS + hd] + al_dd);
        if (slot < CAP) evb[w][hd * EVS + slot] = ev;
        float nm = fmaxf(m, ev);
        ssum = ssum * __expf(m - nm) + __expf(ev - nm);
        m = nm;
    }
    float M = m;
    for (int o = 8; o > 0; o >>= 1) M = fmaxf(M, __shfl_xor(M, o));
    float S = ssum * __expf(m - M);
    for (int o = 8; o > 0; o >>= 1) S += __shfl_xor(S, o);
    float inv = 1.f / (S + 1e-16f);
    int stop = deg < CAP ? deg : CAP;
    for (int slot = j; slot < stop; slot += 16)
        evb[w][hd * EVS + slot] = __expf(evb[w][hd * EVS + slot] - M) * inv;

    // phase 2: alpha-weighted gather of h rows (256 B each), 8-deep pipelined
    // to keep more gather misses in flight (fabric-BW bound)
    int hoff = j * 4;
    float4 acc = {0.f, 0.f, 0.f, 0.f};
    if (deg <= CAP) {
        float4 b1 = {0,0,0,0}, b2 = {0,0,0,0}, b3 = {0,0,0,0};
        int slot = 0;
        for (; slot + 8 <= deg; slot += 8) {
            int s0 = sb[w][slot],     s1 = sb[w][slot + 1];
            int s2 = sb[w][slot + 2], s3 = sb[w][slot + 3];
            int s4 = sb[w][slot + 4], s5 = sb[w][slot + 5];
            int s6 = sb[w][slot + 6], s7 = sb[w][slot + 7];
            float w0 = evb[w][hd * EVS + slot];
            float w1 = evb[w][hd * EVS + slot + 1];
            float w2 = evb[w][hd * EVS + slot + 2];
            float w3 = evb[w][hd * EVS + slot + 3];
            float w4 = evb[w][hd * EVS + slot + 4];
            float w5 = evb[w][hd * EVS + slot + 5];
            float w6 = evb[w][hd * EVS + slot + 6];
            float w7 = evb[w][hd * EVS + slot + 7];
            float4 h0 = *(const float4*)&h[(size_t)s0 * HID + hoff];
            float4 h1 = *(const float4*)&h[(size_t)s1 * HID + hoff];
            float4 h2 = *(const float4*)&h[(size_t)s2 * HID + hoff];
            float4 h3 = *(const float4*)&h[(size_t)s3 * HID + hoff];
            float4 h4 = *(const float4*)&h[(size_t)s4 * HID + hoff];
            float4 h5 = *(const float4*)&h[(size_t)s5 * HID + hoff];
            float4 h6 = *(const float4*)&h[(size_t)s6 * HID + hoff];
            float4 h7 = *(const float4*)&h[(size_t)s7 * HID + hoff];
            acc.x += w0 * h0.x; acc.y += w0 * h0.y; acc.z += w0 * h0.z; acc.w += w0 * h0.w;
            b1.x  += w1 * h1.x; b1.y  += w1 * h1.y; b1.z  += w1 * h1.z; b1.w  += w1 * h1.w;
            b2.x  += w2 * h2.x; b2.y  += w2 * h2.y; b2.z  += w2 * h2.z; b2.w  += w2 * h2.w;
            b3.x  += w3 * h3.x; b3.y  += w3 * h3.y; b3.z  += w3 * h3.z; b3.w  += w3 * h3.w;
            acc.x += w4 * h4.x; acc.y += w4 * h4.y; acc.z += w4 * h4.z; acc.w += w4 * h4.w;
            b1.x  += w5 * h5.x; b1.y  += w5 * h5.y; b1.z  += w5 * h5.z; b1.w  += w5 * h5.w;
            b2.x  += w6 * h6.x; b2.y  += w6 * h6.y; b2.z  += w6 * h6.z; b2.w  += w6 * h6.w;
            b3.x  += w7 * h7.x; b3.y  += w7 * h7.y; b3.z  += w7 * h7.z; b3.w  += w7 * h7.w;
        }
        for (; slot + 4 <= deg; slot += 4) {
            int s0 = sb[w][slot],     s1 = sb[w][slot + 1];
            int s2 = sb[w][slot + 2], s3 = sb[w][slot + 3];
            float w0 = evb[w][hd * EVS + slot];
            float w1 = evb[w][hd * EVS + slot + 1];
            float w2 = evb[w][hd * EVS + slot + 2];
            float w3 = evb[w][hd * EVS + slot + 3];
            float4 h0 = *(const float4*)&h[(size_t)s0 * HID + hoff];
            float4 h1 = *(const float4*)&h[(size_t)s1 * HID + hoff];
            float4 h2 = *(const float4*)&h[(size_t)s2 * HID + hoff];
            float4 h3 = *(const float4*)&h[(size_t)s3 * HID + hoff];
            acc.x += w0 * h0.x; acc.y += w0 * h0.y; acc.z += w0 * h0.z; acc.w += w0 * h0.w;
            b1.x  += w1 * h1.x; b1.y  += w1 * h1.y; b1.z  += w1 * h1.z; b1.w  += w1 * h1.w;
            b2.x  += w2 * h2.x; b2.y  += w2 * h2.y; b2.z  += w2 * h2.z; b2.w  += w2 * h2.w;
            b3.x  += w3 * h3.x; b3.y  += w3 * h3.y; b3.z  += w3 * h3.z; b3.w  += w3 * h3.w;
        }
        for (; slot < deg; slot++) {
            int s0 = sb[w][slot];
            float w0 = evb[w][hd * EVS + slot];
            float4 h0 = *(const float4*)&h[(size_t)s0 * HID + hoff];
            acc.x += w0 * h0.x; acc.y += w0 * h0.y; acc.z += w0 * h0.z; acc.w += w0 * h0.w;
        }
        acc.x += b1.x + b2.x + b3.x;
        acc.y += b1.y + b2.y + b3.y;
        acc.z += b1.z + b2.z + b3.z;
        acc.w += b1.w + b2.w + b3.w;
    } else {
        for (int i = start; i < end; i++) {
            int s = __builtin_amdgcn_readfirstlane(edge_src[i]);
            float ev = lrelu(al_s[s * HEADS + hd] + al_dd);
            float alpha = __expf(ev - M) * inv;
            float4 hr = *(const float4*)&h[(size_t)s * HID + hoff];
            acc.x += alpha * hr.x; acc.y += alpha * hr.y;
            acc.z += alpha * hr.z; acc.w += alpha * hr.w;
        }
    }
    // lane l = hd*16+j holds U[d, hd*64 + j*4 .. +3] == U[d, l*4 .. +3]
    *(float4*)&U[(size_t)d * ZD + l * 4] = acc;
}

// ---------------- global mean pool (batch is sorted; parallel over nodes) -------
// 256 threads = 4 node-lanes x 64 features; each thread walks a 16-node run.
__global__ __launch_bounds__(256) void k_pool(const float* __restrict__ h,
                                              const int* __restrict__ batch,
                                              float* __restrict__ pool,
                                              float* __restrict__ pool_cnt) {
    int t = threadIdx.x;
    int f  = t & 63;               // feature (wave = one node-lane, coalesced rows)
    int nl = t >> 6;               // node-lane 0..3
    int n0 = blockIdx.x * 64 + nl * 16;
    if (n0 >= N_NODES) return;
    int n1 = n0 + 16;
    if (n1 > N_NODES) n1 = N_NODES;
    int curg = batch[n0];
    float acc = 0.f;
    int cnt = 0;
    for (int n = n0; n < n1; n++) {
        int g = batch[n];
        if (g != curg) {
            atomicAdd(&pool[curg * HID + f], acc);
            if (f == 0) atomicAdd(&pool_cnt[curg], (float)cnt);
            acc = 0.f; cnt = 0; curg = g;
        }
        acc += h[(size_t)n * HID + f];
        cnt++;
    }
    atomicAdd(&pool[curg * HID + f], acc);
    if (f == 0) atomicAdd(&pool_cnt[curg], (float)cnt);
}

// ---------------- final FC: out = hg @ W_fc + b_fc ----------------
// Round-5 PMC: FETCH=4x W_fc -- the 4 blocks sharing a W_fc slice were ADJACENT
// in blockIdx, so the XCD round-robin put them on 4 different private L2s.
// Remap so all FC_GS sharers have the same blockIdx%8 (same XCD): within each
// 32-block group, bg=(bid>>3)&3, ob=(bid>>5)*8+(bid&7). Slice fetched once per
// XCD, re-reads hit that XCD's L2.
__global__ __launch_bounds__(256, 1) void k_fc(const float* __restrict__ pool,
                                               const float* __restrict__ pool_cnt,
                                               const float* __restrict__ W_fc,
                                               const float* __restrict__ b_fc,
                                               float* __restrict__ out) {
    __shared__ float hg[FC_GS * HID];
    int t = threadIdx.x;
    int bid = blockIdx.x;
    int bg = (bid >> 3) & (FC_GS - 1);       // graph group (same XCD as its sharers)
    int ob = (bid >> 5) * 8 + (bid & 7);     // output block; bid%8 == ob%8
    int g0 = bg * (G_B / FC_GS);
    if (t < FC_GS * HID) {
        int g = g0 + (t >> 6), f = t & 63;
        hg[t] = pool[g * HID + f] / fmaxf(pool_cnt[g], 1.f);
    }
    __syncthreads();
    int o4 = ob * 256 + t;
    if (o4 >= OUT_F / 4) return;
    int o = o4 * 4;
    float4 acc[FC_GS];
    float4 bo = *(const float4*)&b_fc[o];
    #pragma unroll
    for (int g = 0; g < FC_GS; g++) acc[g] = bo;
    for (int kc = 0; kc < HID; kc += 16) {
        float4 wv[16];
        #pragma unroll
        for (int u = 0; u < 16; u++)
            wv[u] = *(const float4*)&W_fc[(size_t)(kc + u) * OUT_F + o];
        #pragma unroll
        for (int u = 0; u < 16; u++) {
            #pragma unroll
            for (int g = 0; g < FC_GS; g++) {
                float hv = hg[g * HID + kc + u];
                acc[g].x += hv * wv[u].x; acc[g].y += hv * wv[u].y;
                acc[g].z += hv * wv[u].z; acc[g].w += hv * wv[u].w;
            }
        }
    }
    #pragma unroll
    for (int g = 0; g < FC_GS; g++)
        *(float4*)&out[(size_t)(g0 + g) * OUT_F + o] = acc[g];
}

extern "C" void kernel_launch(void* const* d_in, const int* in_sizes, int n_in,
                              void* d_out, int out_size, void* d_ws, size_t ws_size,
                              hipStream_t stream) {
    const float* x       = (const float*)d_in[0];
    const int*   ei      = (const int*)d_in[1];
    // d_in[2] edge_attr: unused by the reference forward
    const int*   batch   = (const int*)d_in[3];
    const float* W_emb   = (const float*)d_in[4];
    const float* b_emb   = (const float*)d_in[5];
    const float* W_gat   = (const float*)d_in[6];
    const float* att_src = (const float*)d_in[7];
    const float* att_dst = (const float*)d_in[8];
    const float* b_gat   = (const float*)d_in[9];
    const float* W_fc    = (const float*)d_in[10];
    const float* b_fc    = (const float*)d_in[11];
    float* out = (float*)d_out;

    char* p = (char*)d_ws;
    auto alloc = [&](size_t bytes) -> void* {
        void* r = (void*)p;
        p += (bytes + 255) & ~(size_t)255;
        return r;
    };
    float* h        = (float*)alloc((size_t)NPAD * HID * 4);
    float* U        = (float*)alloc((size_t)NPAD * ZD * 4);
    float* al_s     = (float*)alloc((size_t)NPAD * HEADS * 4);
    float* al_d     = (float*)alloc((size_t)NPAD * HEADS * 4);
    int*   counts   = (int*)alloc((size_t)N_NODES * 4);
    int*   offsets  = (int*)alloc((size_t)(N_NODES + 1) * 4);
    int*   cursor   = (int*)alloc((size_t)N_NODES * 4);
    int*   tmp      = (int*)alloc((size_t)N_NODES * 4);
    int*   partial  = (int*)alloc((size_t)SCAN_BLK * 4);
    int*   edge_src = (int*)alloc((size_t)EP * 4);
    float* pool     = (float*)alloc((size_t)G_B * HID * 4);
    float* pool_cnt = (float*)alloc((size_t)G_B * 4);
    float* Wstk     = (float*)alloc((size_t)3 * ZD * HID * 4);
    float* weff_s   = (float*)alloc((size_t)3 * HEADS * HID * 4);
    float* weff_d   = (float*)alloc((size_t)3 * HEADS * HID * 4);

    // init + weight prep + CSR build (once per launch; reused by all 3 layers)
    k_init <<<NBLK_SCAN, 256, 0, stream>>>(counts, cursor, pool, pool_cnt,
                                           W_gat, att_src, att_dst,
                                           Wstk, weff_s, weff_d);
    k_count<<<(N_EDGES + 255) / 256, 256, 0, stream>>>(ei, counts);
    k_scan1<<<NBLK_SCAN, SCAN_BLK, 0, stream>>>(counts, tmp, partial);
    k_scan2<<<1, SCAN_BLK, 0, stream>>>(partial);
    k_scan3<<<NBLK_SCAN, 256, 0, stream>>>(tmp, counts, partial, offsets);
    k_fill <<<(EP + 255) / 256, 256, 0, stream>>>(ei, offsets, cursor, edge_src);

    // node embedding + layer-0 attention logits
    k_gemm<IN_F, false, true><<<NPAD / NT, 256, 0, stream>>>(
        x, W_emb, b_emb, weff_s, weff_d, h, al_s, al_d);

    // 3 GAT layers: aggregate in h-space, then mix with Wstk (+ next layer's logits)
    k_agg<<<N_NODES / 4, 256, 0, stream>>>(offsets, edge_src, al_s, al_d, h, U);
    k_gemm<ZD, true, true><<<NPAD / NT, 256, 0, stream>>>(
        U, Wstk, b_gat, weff_s + ZD, weff_d + ZD, h, al_s, al_d);

    k_agg<<<N_NODES / 4, 256, 0, stream>>>(offsets, edge_src, al_s, al_d, h, U);
    k_gemm<ZD, true, true><<<NPAD / NT, 256, 0, stream>>>(
        U, Wstk + (size_t)ZD * HID, b_gat + HID, weff_s + 2 * ZD, weff_d + 2 * ZD,
        h, al_s, al_d);

    k_agg<<<N_NODES / 4, 256, 0, stream>>>(offsets, edge_src, al_s, al_d, h, U);
    k_gemm<ZD, true, false><<<NPAD / NT, 256, 0, stream>>>(
        U, Wstk + (size_t)2 * ZD * HID, b_gat + 2 * HID, weff_s, weff_d,
        h, al_s, al_d);

    // pooling + FC
    k_pool<<<(N_NODES + 63) / 64, 256, 0, stream>>>(h, batch, pool, pool_cnt);
    // grid: round FC_NOB up to a multiple of 8 so the (ob,bg) remap covers all obs
    k_fc  <<<((FC_NOB + 7) / 8) * 8 * FC_GS, 256, 0, stream>>>(
        pool, pool_cnt, W_fc, b_fc, out);
}